// Round 4
// baseline (2730.597 us; speedup 1.0000x reference)
//
#include <hip/hip_runtime.h>
#include <stdint.h>

typedef unsigned long long u64;
typedef unsigned int u32;

static constexpr u64 KEMPTY = ~0ull;
static constexpr int PROBE_CAP = 32768;
static constexpr u32 BINS  = 1024;   // partition on uid & 1023 (hash-uniform)
static constexpr u32 CHUNK = 2048;   // entries per block in hist/part passes

static __device__ __forceinline__ u64 mix64(u64 x){
  x ^= x >> 30; x *= 0xbf58476d1ce4e5b9ull;
  x ^= x >> 27; x *= 0x94d049bb133111ebull;
  x ^= x >> 31; return x;
}

static __device__ __forceinline__ long long lookup_slot(const u64* __restrict__ tk, u32 cmask, u64 code){
  u32 h = (u32)mix64(code) & cmask;
#pragma unroll 1
  for(int p=0;p<PROBE_CAP;p++){
    u64 cur = tk[h];
    if(cur==code) return (long long)h;
    if(cur==KEMPTY) return -1;
    h=(h+1)&cmask;
  }
  return -1;
}

static __device__ __forceinline__ void row_load(const float* __restrict__ p, float* o){
  const float4* q=(const float4*)p;
#pragma unroll
  for(int i=0;i<4;i++){ float4 v=q[i]; o[4*i]=v.x; o[4*i+1]=v.y; o[4*i+2]=v.z; o[4*i+3]=v.w; }
}
static __device__ __forceinline__ void row_store(float* __restrict__ p, const float* o){
  float4* q=(float4*)p;
#pragma unroll
  for(int i=0;i<4;i++) q[i]=make_float4(o[4*i],o[4*i+1],o[4*i+2],o[4*i+3]);
}

// ---------------- kernel 1: elevate/rank/bary + table insert; stores SLOT in inv ----------------
__global__ void __launch_bounds__(256)
k_setup(const float* __restrict__ feat, int N,
        u64* __restrict__ tabk, u32 cmask,
        u32* __restrict__ inv_slot, float* __restrict__ bary)
{
#pragma clang fp contract(off)
  int n = blockIdx.x*256 + threadIdx.x;
  if(n>=N) return;

  const float s0=3.4641016151377544f, s1=2.0f, s2=1.4142135623730951f,
              s3=1.0954451150103321f, s4=0.8944271909999159f;
  float c[5];
  c[0]=feat[n*5+0]*s0; c[1]=feat[n*5+1]*s1; c[2]=feat[n*5+2]*s2;
  c[3]=feat[n*5+3]*s3; c[4]=feat[n*5+4]*s4;

  float sfx[6]; sfx[5]=0.f;
#pragma unroll
  for(int i=4;i>=0;i--) sfx[i]=sfx[i+1]+c[i];
  float el[6];
  el[0]=sfx[0];
#pragma unroll
  for(int i=1;i<6;i++) el[i]=sfx[i]-(float)i*c[i-1];

  const float down=1.0f/6.0f;
  float rd[6], rem0[6], rdsum=0.f;
#pragma unroll
  for(int i=0;i<6;i++){ rd[i]=rintf(el[i]*down); rem0[i]=rd[i]*6.0f; rdsum+=rd[i]; }
  int sumi=(int)rdsum;

  float diff[6];
#pragma unroll
  for(int i=0;i<6;i++) diff[i]=(el[i]-rem0[i])*down;

  int rank[6];
#pragma unroll
  for(int i=0;i<6;i++){
    int r=0;
#pragma unroll
    for(int j=0;j<6;j++)
      r += (diff[j]>diff[i]) || (diff[j]==diff[i] && j<i);
    rank[i]=r+sumi;
  }
  int rem0i[6];
#pragma unroll
  for(int i=0;i<6;i++){
    rem0i[i]=(int)rem0[i];
    int sh=(rank[i]<0)-(rank[i]>5);
    rank[i]+=6*sh; rem0i[i]+=6*sh;
  }

  float b[7]={0.f,0.f,0.f,0.f,0.f,0.f,0.f};
#pragma unroll
  for(int i=0;i<6;i++){
    float t=(el[i]-(float)rem0i[i])*down;
    int k0=5-rank[i]; if(k0>=0&&k0<7) b[k0]+=t;
  }
#pragma unroll
  for(int i=0;i<6;i++){
    float t=(el[i]-(float)rem0i[i])*down;
    int k1=6-rank[i]; if(k1>=0&&k1<7) b[k1]-=t;
  }
  bary[(size_t)n*6+0]=(b[0]+1.0f)+b[6];
#pragma unroll
  for(int r=1;r<6;r++) bary[(size_t)n*6+r]=b[r];

#pragma unroll 1
  for(int r=0;r<6;r++){
    long long code=0;
#pragma unroll
    for(int i=0;i<5;i++){
      int key = rem0i[i] + ((rank[i] >= 6-r) ? (r-6) : r);
      code = code*2048 + (long long)(key+1024);
    }
    u32 h=(u32)mix64((u64)code)&cmask;
    u32 slot=0xFFFFFFFFu;
#pragma unroll 1
    for(int p=0;p<PROBE_CAP;p++){
      u64 cur=tabk[h];
      if(cur==(u64)code){ slot=h; break; }
      if(cur==KEMPTY){
        u64 old=atomicCAS((unsigned long long*)&tabk[h], KEMPTY, (u64)code);
        if(old==KEMPTY || old==(u64)code){ slot=h; break; }
      } else {
        h=(h+1)&cmask;
      }
    }
    inv_slot[(size_t)n*6+r]=slot;
  }
}

// ---------------- kernel 2: compact uids ----------------
__global__ void __launch_bounds__(256)
k_uid(const u64* __restrict__ tabk, u32 C, u32 Ucap, u32* __restrict__ tuid,
      u32* __restrict__ uidslot, u32* __restrict__ counter)
{
  u32 s=blockIdx.x*256+threadIdx.x;
  if(s>=C) return;
  if(tabk[s]==KEMPTY) return;
  u32 uid=atomicAdd(counter,1u);
  if(uid<Ucap) uidslot[uid]=s; else uid=0;
  tuid[s]=uid;
}

// ---------------- pass A: slot->uid translation + per-chunk LDS histogram ----------------
__global__ void __launch_bounds__(256)
k_hist(u32* __restrict__ inv, const u32* __restrict__ tuid,
       u32* __restrict__ hist, size_t M)
{
  __shared__ u32 h[BINS];
  u32 t=threadIdx.x, b=blockIdx.x;
#pragma unroll
  for(int j=0;j<4;j++) h[t+j*256]=0;
  __syncthreads();
  size_t base=(size_t)b*CHUNK;
#pragma unroll
  for(int j=0;j<8;j++){
    size_t i=base + (size_t)j*256 + t;
    if(i<M){
      u32 u=tuid[inv[i]];
      inv[i]=u;
      atomicAdd(&h[u&(BINS-1)],1u);
    }
  }
  __syncthreads();
#pragma unroll
  for(int j=0;j<4;j++){
    u32 bin=t+j*256;
    hist[(size_t)b*BINS+bin]=h[bin];
  }
}

// ---------------- transpose: in[R][C] -> out[C][R] ----------------
__global__ void __launch_bounds__(256)
k_transpose(const u32* __restrict__ in, u32* __restrict__ out, u32 R, u32 C)
{
  __shared__ u32 tile[32][33];
  u32 bx=blockIdx.x, by=blockIdx.y;
  u32 tx=threadIdx.x&31, ty=threadIdx.x>>5;   // 32 x 8
  u32 c0=bx*32, r0=by*32;
#pragma unroll
  for(u32 j=0;j<32;j+=8){
    u32 r=r0+ty+j, c=c0+tx;
    if(r<R && c<C) tile[ty+j][tx]=in[(size_t)r*C+c];
  }
  __syncthreads();
#pragma unroll
  for(u32 j=0;j<32;j+=8){
    u32 c=c0+ty+j, r=r0+tx;
    if(c<C && r<R) out[(size_t)c*R+r]=tile[tx][ty+j];
  }
}

// ---------------- 3-level exclusive scan over histT (K = nb*1024 items) ----------------
__global__ void __launch_bounds__(256)
k_scan1(const u32* __restrict__ v, u32* __restrict__ bsum)
{
  __shared__ u32 sm[256];
  u32 t=threadIdx.x, b=blockIdx.x;
  size_t base=((size_t)b*256+t)*4;
  u32 s=v[base]+v[base+1]+v[base+2]+v[base+3];
  sm[t]=s; __syncthreads();
  for(int o=128;o>0;o>>=1){ if(t<(u32)o) sm[t]+=sm[t+o]; __syncthreads(); }
  if(t==0) bsum[b]=sm[0];
}

__global__ void __launch_bounds__(256)
k_scan2(u32* __restrict__ bsum, u32 nb)
{
  __shared__ u32 sm[256];
  u32 t=threadIdx.x;
  u32 per=(nb+255)/256;
  u32 lo=t*per, hi=lo+per; if(hi>nb) hi=nb; if(lo>nb) lo=nb;
  u32 tot=0;
  for(u32 i=lo;i<hi;i++) tot+=bsum[i];
  sm[t]=tot; __syncthreads();
  for(int o=1;o<256;o<<=1){
    u32 v=sm[t]; u32 a=(t>=(u32)o)?sm[t-o]:0u; __syncthreads();
    sm[t]=v+a; __syncthreads();
  }
  u32 run=sm[t]-tot;
  for(u32 i=lo;i<hi;i++){ u32 c=bsum[i]; bsum[i]=run; run+=c; }
}

__global__ void __launch_bounds__(256)
k_scan3(u32* __restrict__ v, const u32* __restrict__ bsum)
{
  __shared__ u32 sm[256];
  u32 t=threadIdx.x, b=blockIdx.x;
  size_t base=((size_t)b*256+t)*4;
  u32 c[4]; u32 tot=0;
#pragma unroll
  for(int j=0;j<4;j++){ c[j]=v[base+j]; tot+=c[j]; }
  sm[t]=tot; __syncthreads();
  for(int o=1;o<256;o<<=1){
    u32 x=sm[t]; u32 a=(t>=(u32)o)?sm[t-o]:0u; __syncthreads();
    sm[t]=x+a; __syncthreads();
  }
  u32 run=bsum[b]+sm[t]-tot;
#pragma unroll
  for(int j=0;j<4;j++){ v[base+j]=run; run+=c[j]; }
}

// ---------------- pass C: partition entries into bins (LDS cursors, no global atomics) ----------------
// skey packs (uid>>10)<<20 | point_index  (valid for N <= 2^20, Ucap <= 2^20)
__global__ void __launch_bounds__(256)
k_part(const u32* __restrict__ inv, const float* __restrict__ bary,
       const u32* __restrict__ histT, u32 nb,
       u32* __restrict__ skey, float* __restrict__ sw, size_t M)
{
  __shared__ u32 cur[BINS];
  u32 t=threadIdx.x, b=blockIdx.x;
#pragma unroll
  for(int j=0;j<4;j++){
    u32 bin=t+j*256;
    cur[bin]=histT[(size_t)bin*nb+b];
  }
  __syncthreads();
  size_t base=(size_t)b*CHUNK;
#pragma unroll
  for(int j=0;j<8;j++){
    size_t i=base+(size_t)j*256+t;
    if(i<M){
      u32 u=inv[i];
      u32 pos=atomicAdd(&cur[u&(BINS-1)],1u);
      skey[pos]=((u>>10)<<20)|((u32)(i/6u));
      sw[pos]=bary[i];
    }
  }
}

// ---------------- pass D: per-bin LDS accumulate + full flush of val0 ----------------
__global__ void __launch_bounds__(256)
k_accum(const u32* __restrict__ skey, const float* __restrict__ sw,
        const float* __restrict__ values, const u32* __restrict__ histT,
        u32 nb, u32 rows, size_t M, float* __restrict__ v0)
{
  __shared__ float acc[16384];          // rows*16 <= 16384 (64 KB)
  u32 t=threadIdx.x, b=blockIdx.x;
  u32 tot=rows*16;
  for(u32 x=t;x<tot;x+=256) acc[x]=0.f;
  __syncthreads();
  size_t start=histT[(size_t)b*nb];
  size_t end=(b==BINS-1)? M : (size_t)histT[(size_t)(b+1)*nb];
  u32 g=t>>4, k=t&15;
  for(size_t base=start; base<end; base+=16){
    size_t e=base+g;
    if(e<end){
      u32 key=skey[e];
      float w=sw[e];
      u32 row=key>>20, vi=key&0xFFFFFu;
      float v=values[(size_t)vi*16+k];
      atomicAdd(&acc[row*16+k], w*v);
    }
  }
  __syncthreads();
  for(u32 x=t;x<tot;x+=256){
    u32 row=x>>4, kk=x&15;
    v0[(size_t)((row<<10)|b)*16+kk]=acc[x];
  }
}

// ---------------- blur ----------------
__global__ void __launch_bounds__(256)
k_blur(const u64* __restrict__ tabk, const u32* __restrict__ tuid, u32 cmask,
       const u32* __restrict__ uidslot, const u32* __restrict__ counter, u32 Ucap,
       long long delta, const float* __restrict__ vin, float* __restrict__ vout)
{
  u32 m=blockIdx.x*256+threadIdx.x;
  u32 U=*counter; if(U>Ucap) U=Ucap;
  if(m>=U) return;
  long long code=(long long)tabk[uidslot[m]];
  long long sp=lookup_slot(tabk,cmask,(u64)(code+delta));
  long long sm=lookup_slot(tabk,cmask,(u64)(code-delta));
  float acc[16];
  row_load(vin+(size_t)m*16, acc);
#pragma unroll
  for(int k=0;k<16;k++) acc[k]*=0.5f;
  if(sp>=0){
    u32 u=tuid[sp]; float t[16]; row_load(vin+(size_t)u*16,t);
#pragma unroll
    for(int k=0;k<16;k++) acc[k]+=0.25f*t[k];
  }
  if(sm>=0){
    u32 u=tuid[sm]; float t[16]; row_load(vin+(size_t)u*16,t);
#pragma unroll
    for(int k=0;k<16;k++) acc[k]+=0.25f*t[k];
  }
  row_store(vout+(size_t)m*16, acc);
}

// ---------------- slice ----------------
__global__ void __launch_bounds__(256)
k_slice(const u32* __restrict__ inv, const float* __restrict__ bary,
        const float* __restrict__ val, int N, float* __restrict__ out)
{
  int n=blockIdx.x*256+threadIdx.x;
  if(n>=N) return;
  float acc[16];
#pragma unroll
  for(int k=0;k<16;k++) acc[k]=0.f;
#pragma unroll 1
  for(int r=0;r<6;r++){
    u32 u=inv[(size_t)n*6+r];
    float w=bary[(size_t)n*6+r];
    float t[16]; row_load(val+(size_t)u*16,t);
#pragma unroll
    for(int k=0;k<16;k++) acc[k]+=w*t[k];
  }
  const float alpha=0.9696969696969697f;
  float4* q=(float4*)(out+(size_t)n*16);
#pragma unroll
  for(int i=0;i<4;i++) q[i]=make_float4(alpha*acc[4*i],alpha*acc[4*i+1],alpha*acc[4*i+2],alpha*acc[4*i+3]);
}

__global__ void k_diag(float* out, float v){ out[0]=v; }

// ---------------- host ----------------
extern "C" void kernel_launch(void* const* d_in, const int* in_sizes, int n_in,
                              void* d_out, int out_size, void* d_ws, size_t ws_size,
                              hipStream_t stream)
{
  const float* feat   =(const float*)d_in[0];
  const float* values =(const float*)d_in[1];
  float* out=(float*)d_out;
  int N=in_sizes[0]/5;
  size_t M=(size_t)N*6;

  u32 nb=(u32)((M+CHUNK-1)/CHUNK);          // #chunks in hist/part passes
  size_t K=(size_t)nb*BINS;                  // histogram matrix size

  // v1 doubles as scratch: hist[K] histT[K] skey[M] sw[M] bsum[nb]
  auto v1bytes=[&](size_t U)->size_t{
    size_t a=U*64;
    size_t b=K*4+K*4+M*4+M*4+(size_t)nb*4+1024;
    return a>b?a:b;
  };
  auto need=[&](int lC,int lU)->size_t{
    size_t C=1ull<<lC, U=1ull<<lU, s=0;
    auto al=[&](size_t b){ s=(s+255)&~(size_t)255; s+=b; };
    al(4); al(M*4); al(M*4); al(C*8); al(C*4); al(U*4); al(U*64); al(v1bytes(U));
    return s+256;
  };
  const int prefs[4][2]={{22,20},{21,20},{21,19},{20,18}};
  int lC=0,lU=0;
  for(int i=0;i<4;i++){ if(need(prefs[i][0],prefs[i][1])<=ws_size){ lC=prefs[i][0]; lU=prefs[i][1]; break; } }
  if(!lC){
    hipMemsetAsync(d_out,0,(size_t)out_size*sizeof(float),stream);
    k_diag<<<1,1,0,stream>>>(out,(float)(ws_size>>20));
    return;
  }

  size_t C=1ull<<lC, Ucap=1ull<<lU; u32 cmask=(u32)(C-1);
  char* base=(char*)d_ws; size_t offb=0;
  auto carve=[&](size_t b)->char*{ offb=(offb+255)&~(size_t)255; char* p=base+offb; offb+=b; return p; };
  u32*   counter=(u32*)carve(4);
  u32*   inv    =(u32*)carve(M*4);
  float* bary   =(float*)carve(M*4);
  u64*   tabk   =(u64*)carve(C*8);
  u32*   tuid   =(u32*)carve(C*4);
  u32*   uidslot=(u32*)carve(Ucap*4);
  float* v0     =(float*)carve(Ucap*64);
  float* v1     =(float*)carve(v1bytes(Ucap));

  u32*   hist =(u32*)v1;
  u32*   histT=hist+K;
  u32*   skey =histT+K;
  float* sw   =(float*)(skey+M);
  u32*   bsum =(u32*)(sw+M);

  hipMemsetAsync(counter,0,4,stream);
  hipMemsetAsync(tabk,0xFF,C*8,stream);

  const int B=256;
  k_setup<<<(N+B-1)/B,B,0,stream>>>(feat,N,tabk,cmask,inv,bary);
  k_uid  <<<(u32)((C+B-1)/B),B,0,stream>>>(tabk,(u32)C,(u32)Ucap,tuid,uidslot,counter);

  k_hist <<<nb,B,0,stream>>>(inv,tuid,hist,M);
  {
    dim3 g((BINS+31)/32,(nb+31)/32);
    k_transpose<<<g,B,0,stream>>>(hist,histT,nb,BINS);   // hist[nb][BINS] -> histT[BINS][nb]
  }
  u32 sb=(u32)(K/1024);                                  // K is a multiple of 1024
  k_scan1<<<sb,B,0,stream>>>(histT,bsum);
  k_scan2<<<1 ,B,0,stream>>>(bsum,sb);
  k_scan3<<<sb,B,0,stream>>>(histT,bsum);
  k_part <<<nb,B,0,stream>>>(inv,bary,histT,nb,skey,sw,M);

  u32 rows=(u32)(Ucap>>10);
  k_accum<<<BINS,B,0,stream>>>(skey,sw,values,histT,nb,rows,M,v0);

  const long long P[5]={1ll,2048ll,1ll<<22,1ll<<33,1ll<<44};
  const long long SUM=P[0]+P[1]+P[2]+P[3]+P[4];
  u32 gb=(u32)((Ucap+B-1)/B);
  float* a=v0; float* bb=v1;
  for(int j=0;j<6;j++){
    long long delta=(j<5)? (SUM-6*P[4-j]) : SUM;
    k_blur<<<gb,B,0,stream>>>(tabk,tuid,cmask,uidslot,counter,(u32)Ucap,delta,a,bb);
    float* t=a; a=bb; bb=t;
  }
  k_slice<<<(N+B-1)/B,B,0,stream>>>(inv,bary,a,N,out);
}

// Round 5
// 2474.669 us; speedup vs baseline: 1.1034x; 1.1034x over previous
//
#include <hip/hip_runtime.h>
#include <stdint.h>

typedef unsigned long long u64;
typedef unsigned int u32;

static constexpr u64 KEMPTY = ~0ull;
static constexpr int PROBE_CAP = 32768;
static constexpr u32 BINS  = 4096;   // partition on uid & 4095 (hash-uniform)
static constexpr u32 CHUNK = 4096;   // entries per block in hist/part passes

static __device__ __forceinline__ u64 mix64(u64 x){
  x ^= x >> 30; x *= 0xbf58476d1ce4e5b9ull;
  x ^= x >> 27; x *= 0x94d049bb133111ebull;
  x ^= x >> 31; return x;
}

static __device__ __forceinline__ long long lookup_slot(const u64* __restrict__ tk, u32 cmask, u64 code){
  u32 h = (u32)mix64(code) & cmask;
#pragma unroll 1
  for(int p=0;p<PROBE_CAP;p++){
    u64 cur = tk[h];
    if(cur==code) return (long long)h;
    if(cur==KEMPTY) return -1;
    h=(h+1)&cmask;
  }
  return -1;
}

static __device__ __forceinline__ void row_load(const float* __restrict__ p, float* o){
  const float4* q=(const float4*)p;
#pragma unroll
  for(int i=0;i<4;i++){ float4 v=q[i]; o[4*i]=v.x; o[4*i+1]=v.y; o[4*i+2]=v.z; o[4*i+3]=v.w; }
}
static __device__ __forceinline__ void row_store(float* __restrict__ p, const float* o){
  float4* q=(float4*)p;
#pragma unroll
  for(int i=0;i<4;i++) q[i]=make_float4(o[4*i],o[4*i+1],o[4*i+2],o[4*i+3]);
}

// ---------------- kernel 1: elevate/rank/bary + table insert; stores SLOT in inv ----------------
__global__ void __launch_bounds__(256)
k_setup(const float* __restrict__ feat, int N,
        u64* __restrict__ tabk, u32 cmask,
        u32* __restrict__ inv_slot, float* __restrict__ bary)
{
#pragma clang fp contract(off)
  int n = blockIdx.x*256 + threadIdx.x;
  if(n>=N) return;

  const float s0=3.4641016151377544f, s1=2.0f, s2=1.4142135623730951f,
              s3=1.0954451150103321f, s4=0.8944271909999159f;
  float c[5];
  c[0]=feat[n*5+0]*s0; c[1]=feat[n*5+1]*s1; c[2]=feat[n*5+2]*s2;
  c[3]=feat[n*5+3]*s3; c[4]=feat[n*5+4]*s4;

  float sfx[6]; sfx[5]=0.f;
#pragma unroll
  for(int i=4;i>=0;i--) sfx[i]=sfx[i+1]+c[i];
  float el[6];
  el[0]=sfx[0];
#pragma unroll
  for(int i=1;i<6;i++) el[i]=sfx[i]-(float)i*c[i-1];

  const float down=1.0f/6.0f;
  float rd[6], rem0[6], rdsum=0.f;
#pragma unroll
  for(int i=0;i<6;i++){ rd[i]=rintf(el[i]*down); rem0[i]=rd[i]*6.0f; rdsum+=rd[i]; }
  int sumi=(int)rdsum;

  float diff[6];
#pragma unroll
  for(int i=0;i<6;i++) diff[i]=(el[i]-rem0[i])*down;

  int rank[6];
#pragma unroll
  for(int i=0;i<6;i++){
    int r=0;
#pragma unroll
    for(int j=0;j<6;j++)
      r += (diff[j]>diff[i]) || (diff[j]==diff[i] && j<i);
    rank[i]=r+sumi;
  }
  int rem0i[6];
#pragma unroll
  for(int i=0;i<6;i++){
    rem0i[i]=(int)rem0[i];
    int sh=(rank[i]<0)-(rank[i]>5);
    rank[i]+=6*sh; rem0i[i]+=6*sh;
  }

  float b[7]={0.f,0.f,0.f,0.f,0.f,0.f,0.f};
#pragma unroll
  for(int i=0;i<6;i++){
    float t=(el[i]-(float)rem0i[i])*down;
    int k0=5-rank[i]; if(k0>=0&&k0<7) b[k0]+=t;
  }
#pragma unroll
  for(int i=0;i<6;i++){
    float t=(el[i]-(float)rem0i[i])*down;
    int k1=6-rank[i]; if(k1>=0&&k1<7) b[k1]-=t;
  }
  bary[(size_t)n*6+0]=(b[0]+1.0f)+b[6];
#pragma unroll
  for(int r=1;r<6;r++) bary[(size_t)n*6+r]=b[r];

#pragma unroll 1
  for(int r=0;r<6;r++){
    long long code=0;
#pragma unroll
    for(int i=0;i<5;i++){
      int key = rem0i[i] + ((rank[i] >= 6-r) ? (r-6) : r);
      code = code*2048 + (long long)(key+1024);
    }
    u32 h=(u32)mix64((u64)code)&cmask;
    u32 slot=0xFFFFFFFFu;
#pragma unroll 1
    for(int p=0;p<PROBE_CAP;p++){
      u64 cur=tabk[h];
      if(cur==(u64)code){ slot=h; break; }
      if(cur==KEMPTY){
        u64 old=atomicCAS((unsigned long long*)&tabk[h], KEMPTY, (u64)code);
        if(old==KEMPTY || old==(u64)code){ slot=h; break; }
      } else {
        h=(h+1)&cmask;
      }
    }
    inv_slot[(size_t)n*6+r]=slot;
  }
}

// ---------------- kernel 2: compact uids ----------------
__global__ void __launch_bounds__(256)
k_uid(const u64* __restrict__ tabk, u32 C, u32 Ucap, u32* __restrict__ tuid,
      u32* __restrict__ uidslot, u32* __restrict__ counter)
{
  u32 s=blockIdx.x*256+threadIdx.x;
  if(s>=C) return;
  if(tabk[s]==KEMPTY) return;
  u32 uid=atomicAdd(counter,1u);
  if(uid<Ucap) uidslot[uid]=s; else uid=0;
  tuid[s]=uid;
}

// ---------------- pass A: slot->uid translation + per-chunk LDS histogram ----------------
__global__ void __launch_bounds__(256)
k_hist(u32* __restrict__ inv, const u32* __restrict__ tuid,
       u32* __restrict__ hist, size_t M)
{
  __shared__ u32 h[BINS];
  u32 t=threadIdx.x, b=blockIdx.x;
#pragma unroll
  for(int j=0;j<(int)(BINS/256);j++) h[t+j*256]=0;
  __syncthreads();
  size_t base=(size_t)b*CHUNK;
#pragma unroll
  for(int j=0;j<(int)(CHUNK/256);j++){
    size_t i=base + (size_t)j*256 + t;
    if(i<M){
      u32 u=tuid[inv[i]];
      inv[i]=u;
      atomicAdd(&h[u&(BINS-1)],1u);
    }
  }
  __syncthreads();
#pragma unroll
  for(int j=0;j<(int)(BINS/256);j++){
    u32 bin=t+j*256;
    hist[(size_t)b*BINS+bin]=h[bin];
  }
}

// ---------------- transpose: in[R][C] -> out[C][R] ----------------
__global__ void __launch_bounds__(256)
k_transpose(const u32* __restrict__ in, u32* __restrict__ out, u32 R, u32 C)
{
  __shared__ u32 tile[32][33];
  u32 bx=blockIdx.x, by=blockIdx.y;
  u32 tx=threadIdx.x&31, ty=threadIdx.x>>5;   // 32 x 8
  u32 c0=bx*32, r0=by*32;
#pragma unroll
  for(u32 j=0;j<32;j+=8){
    u32 r=r0+ty+j, c=c0+tx;
    if(r<R && c<C) tile[ty+j][tx]=in[(size_t)r*C+c];
  }
  __syncthreads();
#pragma unroll
  for(u32 j=0;j<32;j+=8){
    u32 c=c0+ty+j, r=r0+tx;
    if(c<C && r<R) out[(size_t)c*R+r]=tile[tx][ty+j];
  }
}

// ---------------- 3-level exclusive scan over histT (K = nb*BINS items, mult of 1024) ----------------
__global__ void __launch_bounds__(256)
k_scan1(const u32* __restrict__ v, u32* __restrict__ bsum)
{
  __shared__ u32 sm[256];
  u32 t=threadIdx.x, b=blockIdx.x;
  size_t base=((size_t)b*256+t)*4;
  u32 s=v[base]+v[base+1]+v[base+2]+v[base+3];
  sm[t]=s; __syncthreads();
  for(int o=128;o>0;o>>=1){ if(t<(u32)o) sm[t]+=sm[t+o]; __syncthreads(); }
  if(t==0) bsum[b]=sm[0];
}

__global__ void __launch_bounds__(256)
k_scan2(u32* __restrict__ bsum, u32 nb)
{
  __shared__ u32 sm[256];
  u32 t=threadIdx.x;
  u32 per=(nb+255)/256;
  u32 lo=t*per, hi=lo+per; if(hi>nb) hi=nb; if(lo>nb) lo=nb;
  u32 tot=0;
  for(u32 i=lo;i<hi;i++) tot+=bsum[i];
  sm[t]=tot; __syncthreads();
  for(int o=1;o<256;o<<=1){
    u32 v=sm[t]; u32 a=(t>=(u32)o)?sm[t-o]:0u; __syncthreads();
    sm[t]=v+a; __syncthreads();
  }
  u32 run=sm[t]-tot;
  for(u32 i=lo;i<hi;i++){ u32 c=bsum[i]; bsum[i]=run; run+=c; }
}

__global__ void __launch_bounds__(256)
k_scan3(u32* __restrict__ v, const u32* __restrict__ bsum)
{
  __shared__ u32 sm[256];
  u32 t=threadIdx.x, b=blockIdx.x;
  size_t base=((size_t)b*256+t)*4;
  u32 c[4]; u32 tot=0;
#pragma unroll
  for(int j=0;j<4;j++){ c[j]=v[base+j]; tot+=c[j]; }
  sm[t]=tot; __syncthreads();
  for(int o=1;o<256;o<<=1){
    u32 x=sm[t]; u32 a=(t>=(u32)o)?sm[t-o]:0u; __syncthreads();
    sm[t]=x+a; __syncthreads();
  }
  u32 run=bsum[b]+sm[t]-tot;
#pragma unroll
  for(int j=0;j<4;j++){ v[base+j]=run; run+=c[j]; }
}

// ---------------- pass C: partition entries into bins (LDS cursors, no global atomics) ----------------
// skey packs (uid>>12)<<20 | point_index  (valid for N <= 2^20, Ucap <= 2^20)
__global__ void __launch_bounds__(256)
k_part(const u32* __restrict__ inv, const float* __restrict__ bary,
       const u32* __restrict__ histT, u32 nb,
       u32* __restrict__ skey, float* __restrict__ sw, size_t M)
{
  __shared__ u32 cur[BINS];
  u32 t=threadIdx.x, b=blockIdx.x;
#pragma unroll
  for(int j=0;j<(int)(BINS/256);j++){
    u32 bin=t+j*256;
    cur[bin]=histT[(size_t)bin*nb+b];
  }
  __syncthreads();
  size_t base=(size_t)b*CHUNK;
#pragma unroll
  for(int j=0;j<(int)(CHUNK/256);j++){
    size_t i=base+(size_t)j*256+t;
    if(i<M){
      u32 u=inv[i];
      u32 pos=atomicAdd(&cur[u&(BINS-1)],1u);
      skey[pos]=((u>>12)<<20)|((u32)(i/6u));
      sw[pos]=bary[i];
    }
  }
}

// ---------------- pass D: per-bin LDS accumulate + full flush of val0 ----------------
__global__ void __launch_bounds__(256)
k_accum(const u32* __restrict__ skey, const float* __restrict__ sw,
        const float* __restrict__ values, const u32* __restrict__ histT,
        u32 nb, u32 rows, size_t M, float* __restrict__ v0)
{
  __shared__ float acc[4096];           // rows*16 <= 4096 (16 KB) -> 10 blocks/CU
  u32 t=threadIdx.x, b=blockIdx.x;
  u32 tot=rows*16;
  for(u32 x=t;x<tot;x+=256) acc[x]=0.f;
  __syncthreads();
  size_t start=histT[(size_t)b*nb];
  size_t end=(b==BINS-1)? M : (size_t)histT[(size_t)(b+1)*nb];
  u32 g=t>>4, k=t&15;
  // 2 independent gathers in flight per thread per iteration
  for(size_t base=start; base<end; base+=32){
    size_t e0=base+g, e1=base+16+g;
    u32 key0=0; float w0=0.f, x0=0.f; bool ok0=e0<end;
    u32 key1=0; float w1=0.f, x1=0.f; bool ok1=e1<end;
    if(ok0){ key0=skey[e0]; w0=sw[e0]; x0=values[(size_t)(key0&0xFFFFFu)*16+k]; }
    if(ok1){ key1=skey[e1]; w1=sw[e1]; x1=values[(size_t)(key1&0xFFFFFu)*16+k]; }
    if(ok0) atomicAdd(&acc[(key0>>20)*16+k], w0*x0);
    if(ok1) atomicAdd(&acc[(key1>>20)*16+k], w1*x1);
  }
  __syncthreads();
  for(u32 x=t;x<tot;x+=256){
    u32 row=x>>4, kk=x&15;
    v0[(size_t)((row<<12)|b)*16+kk]=acc[x];
  }
}

// ---------------- blur ----------------
__global__ void __launch_bounds__(256)
k_blur(const u64* __restrict__ tabk, const u32* __restrict__ tuid, u32 cmask,
       const u32* __restrict__ uidslot, const u32* __restrict__ counter, u32 Ucap,
       long long delta, const float* __restrict__ vin, float* __restrict__ vout)
{
  u32 m=blockIdx.x*256+threadIdx.x;
  u32 U=*counter; if(U>Ucap) U=Ucap;
  if(m>=U) return;
  long long code=(long long)tabk[uidslot[m]];
  long long sp=lookup_slot(tabk,cmask,(u64)(code+delta));
  long long sm=lookup_slot(tabk,cmask,(u64)(code-delta));
  float acc[16];
  row_load(vin+(size_t)m*16, acc);
#pragma unroll
  for(int k=0;k<16;k++) acc[k]*=0.5f;
  if(sp>=0){
    u32 u=tuid[sp]; float t[16]; row_load(vin+(size_t)u*16,t);
#pragma unroll
    for(int k=0;k<16;k++) acc[k]+=0.25f*t[k];
  }
  if(sm>=0){
    u32 u=tuid[sm]; float t[16]; row_load(vin+(size_t)u*16,t);
#pragma unroll
    for(int k=0;k<16;k++) acc[k]+=0.25f*t[k];
  }
  row_store(vout+(size_t)m*16, acc);
}

// ---------------- slice ----------------
__global__ void __launch_bounds__(256)
k_slice(const u32* __restrict__ inv, const float* __restrict__ bary,
        const float* __restrict__ val, int N, float* __restrict__ out)
{
  int n=blockIdx.x*256+threadIdx.x;
  if(n>=N) return;
  float acc[16];
#pragma unroll
  for(int k=0;k<16;k++) acc[k]=0.f;
#pragma unroll 1
  for(int r=0;r<6;r++){
    u32 u=inv[(size_t)n*6+r];
    float w=bary[(size_t)n*6+r];
    float t[16]; row_load(val+(size_t)u*16,t);
#pragma unroll
    for(int k=0;k<16;k++) acc[k]+=w*t[k];
  }
  const float alpha=0.9696969696969697f;
  float4* q=(float4*)(out+(size_t)n*16);
#pragma unroll
  for(int i=0;i<4;i++) q[i]=make_float4(alpha*acc[4*i],alpha*acc[4*i+1],alpha*acc[4*i+2],alpha*acc[4*i+3]);
}

__global__ void k_diag(float* out, float v){ out[0]=v; }

// ---------------- host ----------------
extern "C" void kernel_launch(void* const* d_in, const int* in_sizes, int n_in,
                              void* d_out, int out_size, void* d_ws, size_t ws_size,
                              hipStream_t stream)
{
  const float* feat   =(const float*)d_in[0];
  const float* values =(const float*)d_in[1];
  float* out=(float*)d_out;
  int N=in_sizes[0]/5;
  size_t M=(size_t)N*6;

  u32 nb=(u32)((M+CHUNK-1)/CHUNK);          // #chunks in hist/part passes
  size_t K=(size_t)nb*BINS;                  // histogram matrix size

  // v1 doubles as scratch: hist[K] histT[K] skey[M] sw[M] bsum[K/1024]
  auto v1bytes=[&](size_t U)->size_t{
    size_t a=U*64;
    size_t b=K*4+K*4+M*4+M*4+(K/1024)*4+1024;
    return a>b?a:b;
  };
  auto need=[&](int lC,int lU)->size_t{
    size_t C=1ull<<lC, U=1ull<<lU, s=0;
    auto al=[&](size_t b){ s=(s+255)&~(size_t)255; s+=b; };
    al(4); al(M*4); al(M*4); al(C*8); al(C*4); al(U*4); al(U*64); al(v1bytes(U));
    return s+256;
  };
  const int prefs[4][2]={{22,20},{21,20},{21,19},{20,18}};
  int lC=0,lU=0;
  for(int i=0;i<4;i++){ if(need(prefs[i][0],prefs[i][1])<=ws_size){ lC=prefs[i][0]; lU=prefs[i][1]; break; } }
  if(!lC){
    hipMemsetAsync(d_out,0,(size_t)out_size*sizeof(float),stream);
    k_diag<<<1,1,0,stream>>>(out,(float)(ws_size>>20));
    return;
  }

  size_t C=1ull<<lC, Ucap=1ull<<lU; u32 cmask=(u32)(C-1);
  char* base=(char*)d_ws; size_t offb=0;
  auto carve=[&](size_t b)->char*{ offb=(offb+255)&~(size_t)255; char* p=base+offb; offb+=b; return p; };
  u32*   counter=(u32*)carve(4);
  u32*   inv    =(u32*)carve(M*4);
  float* bary   =(float*)carve(M*4);
  u64*   tabk   =(u64*)carve(C*8);
  u32*   tuid   =(u32*)carve(C*4);
  u32*   uidslot=(u32*)carve(Ucap*4);
  float* v0     =(float*)carve(Ucap*64);
  float* v1     =(float*)carve(v1bytes(Ucap));

  u32*   hist =(u32*)v1;
  u32*   histT=hist+K;
  u32*   skey =histT+K;
  float* sw   =(float*)(skey+M);
  u32*   bsum =(u32*)(sw+M);

  hipMemsetAsync(counter,0,4,stream);
  hipMemsetAsync(tabk,0xFF,C*8,stream);

  const int B=256;
  k_setup<<<(N+B-1)/B,B,0,stream>>>(feat,N,tabk,cmask,inv,bary);
  k_uid  <<<(u32)((C+B-1)/B),B,0,stream>>>(tabk,(u32)C,(u32)Ucap,tuid,uidslot,counter);

  k_hist <<<nb,B,0,stream>>>(inv,tuid,hist,M);
  {
    dim3 g((BINS+31)/32,(nb+31)/32);
    k_transpose<<<g,B,0,stream>>>(hist,histT,nb,BINS);   // hist[nb][BINS] -> histT[BINS][nb]
  }
  u32 sb=(u32)(K/1024);                                  // K is a multiple of 1024
  k_scan1<<<sb,B,0,stream>>>(histT,bsum);
  k_scan2<<<1 ,B,0,stream>>>(bsum,sb);
  k_scan3<<<sb,B,0,stream>>>(histT,bsum);
  k_part <<<nb,B,0,stream>>>(inv,bary,histT,nb,skey,sw,M);

  u32 rows=(u32)(Ucap>>12);
  k_accum<<<BINS,B,0,stream>>>(skey,sw,values,histT,nb,rows,M,v0);

  const long long P[5]={1ll,2048ll,1ll<<22,1ll<<33,1ll<<44};
  const long long SUM=P[0]+P[1]+P[2]+P[3]+P[4];
  u32 gb=(u32)((Ucap+B-1)/B);
  float* a=v0; float* bb=v1;
  for(int j=0;j<6;j++){
    long long delta=(j<5)? (SUM-6*P[4-j]) : SUM;
    k_blur<<<gb,B,0,stream>>>(tabk,tuid,cmask,uidslot,counter,(u32)Ucap,delta,a,bb);
    float* t=a; a=bb; bb=t;
  }
  k_slice<<<(N+B-1)/B,B,0,stream>>>(inv,bary,a,N,out);
}

// Round 6
// 1741.201 us; speedup vs baseline: 1.5682x; 1.4212x over previous
//
#include <hip/hip_runtime.h>
#include <stdint.h>

typedef unsigned long long u64;
typedef unsigned int u32;

static constexpr u64 KEMPTY = ~0ull;
static constexpr int PROBE_CAP = 32768;
static constexpr u32 BINS  = 4096;   // partition on uid & 4095 (hash-uniform)
static constexpr u32 CHUNK = 4096;   // entries per block in hist/part passes
static constexpr u32 SPLIT = 8192;   // max entries per accum work-item

static __device__ __forceinline__ u64 mix64(u64 x){
  x ^= x >> 30; x *= 0xbf58476d1ce4e5b9ull;
  x ^= x >> 27; x *= 0x94d049bb133111ebull;
  x ^= x >> 31; return x;
}

static __device__ __forceinline__ long long lookup_slot(const u64* __restrict__ tk, u32 cmask, u64 code){
  u32 h = (u32)mix64(code) & cmask;
#pragma unroll 1
  for(int p=0;p<PROBE_CAP;p++){
    u64 cur = tk[h];
    if(cur==code) return (long long)h;
    if(cur==KEMPTY) return -1;
    h=(h+1)&cmask;
  }
  return -1;
}

static __device__ __forceinline__ void atomAddF(float* p, float v){
#if defined(__gfx90a__) || defined(__gfx940__) || defined(__gfx941__) || defined(__gfx942__) || defined(__gfx950__)
  unsafeAtomicAdd(p, v);
#else
  atomicAdd(p, v);
#endif
}

static __device__ __forceinline__ void row_load(const float* __restrict__ p, float* o){
  const float4* q=(const float4*)p;
#pragma unroll
  for(int i=0;i<4;i++){ float4 v=q[i]; o[4*i]=v.x; o[4*i+1]=v.y; o[4*i+2]=v.z; o[4*i+3]=v.w; }
}
static __device__ __forceinline__ void row_store(float* __restrict__ p, const float* o){
  float4* q=(float4*)p;
#pragma unroll
  for(int i=0;i<4;i++) q[i]=make_float4(o[4*i],o[4*i+1],o[4*i+2],o[4*i+3]);
}

// ---------------- kernel 1: elevate/rank/bary + table insert; stores SLOT in inv ----------------
__global__ void __launch_bounds__(256)
k_setup(const float* __restrict__ feat, int N,
        u64* __restrict__ tabk, u32 cmask,
        u32* __restrict__ inv_slot, float* __restrict__ bary)
{
#pragma clang fp contract(off)
  int n = blockIdx.x*256 + threadIdx.x;
  if(n>=N) return;

  const float s0=3.4641016151377544f, s1=2.0f, s2=1.4142135623730951f,
              s3=1.0954451150103321f, s4=0.8944271909999159f;
  float c[5];
  c[0]=feat[n*5+0]*s0; c[1]=feat[n*5+1]*s1; c[2]=feat[n*5+2]*s2;
  c[3]=feat[n*5+3]*s3; c[4]=feat[n*5+4]*s4;

  float sfx[6]; sfx[5]=0.f;
#pragma unroll
  for(int i=4;i>=0;i--) sfx[i]=sfx[i+1]+c[i];
  float el[6];
  el[0]=sfx[0];
#pragma unroll
  for(int i=1;i<6;i++) el[i]=sfx[i]-(float)i*c[i-1];

  const float down=1.0f/6.0f;
  float rd[6], rem0[6], rdsum=0.f;
#pragma unroll
  for(int i=0;i<6;i++){ rd[i]=rintf(el[i]*down); rem0[i]=rd[i]*6.0f; rdsum+=rd[i]; }
  int sumi=(int)rdsum;

  float diff[6];
#pragma unroll
  for(int i=0;i<6;i++) diff[i]=(el[i]-rem0[i])*down;

  int rank[6];
#pragma unroll
  for(int i=0;i<6;i++){
    int r=0;
#pragma unroll
    for(int j=0;j<6;j++)
      r += (diff[j]>diff[i]) || (diff[j]==diff[i] && j<i);
    rank[i]=r+sumi;
  }
  int rem0i[6];
#pragma unroll
  for(int i=0;i<6;i++){
    rem0i[i]=(int)rem0[i];
    int sh=(rank[i]<0)-(rank[i]>5);
    rank[i]+=6*sh; rem0i[i]+=6*sh;
  }

  float b[7]={0.f,0.f,0.f,0.f,0.f,0.f,0.f};
#pragma unroll
  for(int i=0;i<6;i++){
    float t=(el[i]-(float)rem0i[i])*down;
    int k0=5-rank[i]; if(k0>=0&&k0<7) b[k0]+=t;
  }
#pragma unroll
  for(int i=0;i<6;i++){
    float t=(el[i]-(float)rem0i[i])*down;
    int k1=6-rank[i]; if(k1>=0&&k1<7) b[k1]-=t;
  }
  bary[(size_t)n*6+0]=(b[0]+1.0f)+b[6];
#pragma unroll
  for(int r=1;r<6;r++) bary[(size_t)n*6+r]=b[r];

#pragma unroll 1
  for(int r=0;r<6;r++){
    long long code=0;
#pragma unroll
    for(int i=0;i<5;i++){
      int key = rem0i[i] + ((rank[i] >= 6-r) ? (r-6) : r);
      code = code*2048 + (long long)(key+1024);
    }
    u32 h=(u32)mix64((u64)code)&cmask;
    u32 slot=0xFFFFFFFFu;
#pragma unroll 1
    for(int p=0;p<PROBE_CAP;p++){
      u64 cur=tabk[h];
      if(cur==(u64)code){ slot=h; break; }
      if(cur==KEMPTY){
        u64 old=atomicCAS((unsigned long long*)&tabk[h], KEMPTY, (u64)code);
        if(old==KEMPTY || old==(u64)code){ slot=h; break; }
      } else {
        h=(h+1)&cmask;
      }
    }
    inv_slot[(size_t)n*6+r]=slot;
  }
}

// ---------------- kernel 2: compact uids ----------------
__global__ void __launch_bounds__(256)
k_uid(const u64* __restrict__ tabk, u32 C, u32 Ucap, u32* __restrict__ tuid,
      u32* __restrict__ uidslot, u32* __restrict__ counter)
{
  u32 s=blockIdx.x*256+threadIdx.x;
  if(s>=C) return;
  if(tabk[s]==KEMPTY) return;
  u32 uid=atomicAdd(counter,1u);
  if(uid<Ucap) uidslot[uid]=s; else uid=0;
  tuid[s]=uid;
}

// ---------------- pass A: slot->uid translation + per-chunk LDS histogram ----------------
__global__ void __launch_bounds__(256)
k_hist(u32* __restrict__ inv, const u32* __restrict__ tuid,
       u32* __restrict__ hist, size_t M)
{
  __shared__ u32 h[BINS];
  u32 t=threadIdx.x, b=blockIdx.x;
#pragma unroll
  for(int j=0;j<(int)(BINS/256);j++) h[t+j*256]=0;
  __syncthreads();
  size_t base=(size_t)b*CHUNK;
#pragma unroll
  for(int j=0;j<(int)(CHUNK/256);j++){
    size_t i=base + (size_t)j*256 + t;
    if(i<M){
      u32 u=tuid[inv[i]];
      inv[i]=u;
      atomicAdd(&h[u&(BINS-1)],1u);
    }
  }
  __syncthreads();
#pragma unroll
  for(int j=0;j<(int)(BINS/256);j++){
    u32 bin=t+j*256;
    hist[(size_t)b*BINS+bin]=h[bin];
  }
}

// ---------------- transpose: in[R][C] -> out[C][R] ----------------
__global__ void __launch_bounds__(256)
k_transpose(const u32* __restrict__ in, u32* __restrict__ out, u32 R, u32 C)
{
  __shared__ u32 tile[32][33];
  u32 bx=blockIdx.x, by=blockIdx.y;
  u32 tx=threadIdx.x&31, ty=threadIdx.x>>5;   // 32 x 8
  u32 c0=bx*32, r0=by*32;
#pragma unroll
  for(u32 j=0;j<32;j+=8){
    u32 r=r0+ty+j, c=c0+tx;
    if(r<R && c<C) tile[ty+j][tx]=in[(size_t)r*C+c];
  }
  __syncthreads();
#pragma unroll
  for(u32 j=0;j<32;j+=8){
    u32 c=c0+ty+j, r=r0+tx;
    if(c<C && r<R) out[(size_t)c*R+r]=tile[tx][ty+j];
  }
}

// ---------------- 3-level exclusive scan over histT (K items, mult of 1024) ----------------
__global__ void __launch_bounds__(256)
k_scan1(const u32* __restrict__ v, u32* __restrict__ bsum)
{
  __shared__ u32 sm[256];
  u32 t=threadIdx.x, b=blockIdx.x;
  size_t base=((size_t)b*256+t)*4;
  u32 s=v[base]+v[base+1]+v[base+2]+v[base+3];
  sm[t]=s; __syncthreads();
  for(int o=128;o>0;o>>=1){ if(t<(u32)o) sm[t]+=sm[t+o]; __syncthreads(); }
  if(t==0) bsum[b]=sm[0];
}

__global__ void __launch_bounds__(256)
k_scan2(u32* __restrict__ bsum, u32 nb)
{
  __shared__ u32 sm[256];
  u32 t=threadIdx.x;
  u32 per=(nb+255)/256;
  u32 lo=t*per, hi=lo+per; if(hi>nb) hi=nb; if(lo>nb) lo=nb;
  u32 tot=0;
  for(u32 i=lo;i<hi;i++) tot+=bsum[i];
  sm[t]=tot; __syncthreads();
  for(int o=1;o<256;o<<=1){
    u32 v=sm[t]; u32 a=(t>=(u32)o)?sm[t-o]:0u; __syncthreads();
    sm[t]=v+a; __syncthreads();
  }
  u32 run=sm[t]-tot;
  for(u32 i=lo;i<hi;i++){ u32 c=bsum[i]; bsum[i]=run; run+=c; }
}

__global__ void __launch_bounds__(256)
k_scan3(u32* __restrict__ v, const u32* __restrict__ bsum)
{
  __shared__ u32 sm[256];
  u32 t=threadIdx.x, b=blockIdx.x;
  size_t base=((size_t)b*256+t)*4;
  u32 c[4]; u32 tot=0;
#pragma unroll
  for(int j=0;j<4;j++){ c[j]=v[base+j]; tot+=c[j]; }
  sm[t]=tot; __syncthreads();
  for(int o=1;o<256;o<<=1){
    u32 x=sm[t]; u32 a=(t>=(u32)o)?sm[t-o]:0u; __syncthreads();
    sm[t]=x+a; __syncthreads();
  }
  u32 run=bsum[b]+sm[t]-tot;
#pragma unroll
  for(int j=0;j<4;j++){ v[base+j]=run; run+=c[j]; }
}

// ---------------- pass C: partition entries into bins (LDS cursors, no global atomics) ----------------
// skey packs (uid>>12)<<20 | point_index  (valid for N <= 2^20, Ucap <= 2^20)
__global__ void __launch_bounds__(256)
k_part(const u32* __restrict__ inv, const float* __restrict__ bary,
       const u32* __restrict__ histT, u32 nb,
       u32* __restrict__ skey, float* __restrict__ sw, size_t M)
{
  __shared__ u32 cur[BINS];
  u32 t=threadIdx.x, b=blockIdx.x;
#pragma unroll
  for(int j=0;j<(int)(BINS/256);j++){
    u32 bin=t+j*256;
    cur[bin]=histT[(size_t)bin*nb+b];
  }
  __syncthreads();
  size_t base=(size_t)b*CHUNK;
#pragma unroll
  for(int j=0;j<(int)(CHUNK/256);j++){
    size_t i=base+(size_t)j*256+t;
    if(i<M){
      u32 u=inv[i];
      u32 pos=atomicAdd(&cur[u&(BINS-1)],1u);
      skey[pos]=((u>>12)<<20)|((u32)(i/6u));
      sw[pos]=bary[i];
    }
  }
}

// ---------------- queue build: split each bin into G=ceil(size/SPLIT) balanced slices ----------------
// q entry: bin[0:12) | g[12:22) | G[22:32)
__global__ void __launch_bounds__(256)
k_queue(const u32* __restrict__ histT, u32 nb, size_t M,
        u32* __restrict__ q, u32* __restrict__ qn)
{
  u32 b=blockIdx.x*256+threadIdx.x;
  if(b>=BINS) return;
  size_t s=histT[(size_t)b*nb];
  size_t e=(b+1<BINS)? (size_t)histT[(size_t)(b+1)*nb] : M;
  u32 sz=(u32)(e-s);
  if(sz==0) return;
  u32 G=(sz+SPLIT-1)/SPLIT; if(G>1023u) G=1023u;
  u32 base=atomicAdd(qn,G);
  for(u32 g=0; g<G; g++) q[base+g] = b | (g<<12) | (G<<22);
}

// ---------------- pass D: per-slice LDS accumulate + flush ----------------
__global__ void __launch_bounds__(256)
k_accum(const u32* __restrict__ q, const u32* __restrict__ qn,
        const u32* __restrict__ skey, const float* __restrict__ sw,
        const float* __restrict__ values, const u32* __restrict__ histT,
        u32 nb, u32 rows, size_t M, float* __restrict__ v0)
{
  __shared__ float acc[4096];           // rows*16 <= 4096 (16 KB)
  u32 j=blockIdx.x;
  if(j>=*qn) return;
  u32 ent=q[j];
  u32 b=ent&4095u, g=(ent>>12)&1023u, G=ent>>22;
  size_t s0=histT[(size_t)b*nb];
  size_t e0=(b+1<BINS)? (size_t)histT[(size_t)(b+1)*nb] : M;
  u32 sz=(u32)(e0-s0);
  u32 chunk=(sz+G-1)/G;
  size_t s=s0+(size_t)g*chunk;
  size_t e=s+chunk; if(e>e0) e=e0;

  u32 t=threadIdx.x;
  u32 tot=rows*16;
  for(u32 x=t;x<tot;x+=256) acc[x]=0.f;
  __syncthreads();

  u32 gr=t>>4, k=t&15;
  for(size_t base=s+ (size_t)0; base<e; base+=32){
    size_t e0i=base+gr, e1i=base+16+gr;
    u32 key0=0; float w0=0.f, x0=0.f; bool ok0=e0i<e;
    u32 key1=0; float w1=0.f, x1=0.f; bool ok1=e1i<e;
    if(ok0){ key0=skey[e0i]; w0=sw[e0i]; x0=values[(size_t)(key0&0xFFFFFu)*16+k]; }
    if(ok1){ key1=skey[e1i]; w1=sw[e1i]; x1=values[(size_t)(key1&0xFFFFFu)*16+k]; }
    if(ok0) atomicAdd(&acc[(key0>>20)*16+k], w0*x0);
    if(ok1) atomicAdd(&acc[(key1>>20)*16+k], w1*x1);
  }
  __syncthreads();

  if(G==1){
    for(u32 x=t;x<tot;x+=256){
      u32 row=x>>4, kk=x&15;
      v0[(size_t)((row<<12)|b)*16+kk]=acc[x];
    }
  } else {
    for(u32 x=t;x<tot;x+=256){
      float a=acc[x];
      if(a!=0.f){
        u32 row=x>>4, kk=x&15;
        atomAddF(&v0[(size_t)((row<<12)|b)*16+kk], a);
      }
    }
  }
}

// ---------------- blur ----------------
__global__ void __launch_bounds__(256)
k_blur(const u64* __restrict__ tabk, const u32* __restrict__ tuid, u32 cmask,
       const u32* __restrict__ uidslot, const u32* __restrict__ counter, u32 Ucap,
       long long delta, const float* __restrict__ vin, float* __restrict__ vout)
{
  u32 m=blockIdx.x*256+threadIdx.x;
  u32 U=*counter; if(U>Ucap) U=Ucap;
  if(m>=U) return;
  long long code=(long long)tabk[uidslot[m]];
  long long sp=lookup_slot(tabk,cmask,(u64)(code+delta));
  long long sm=lookup_slot(tabk,cmask,(u64)(code-delta));
  float acc[16];
  row_load(vin+(size_t)m*16, acc);
#pragma unroll
  for(int k=0;k<16;k++) acc[k]*=0.5f;
  if(sp>=0){
    u32 u=tuid[sp]; float t[16]; row_load(vin+(size_t)u*16,t);
#pragma unroll
    for(int k=0;k<16;k++) acc[k]+=0.25f*t[k];
  }
  if(sm>=0){
    u32 u=tuid[sm]; float t[16]; row_load(vin+(size_t)u*16,t);
#pragma unroll
    for(int k=0;k<16;k++) acc[k]+=0.25f*t[k];
  }
  row_store(vout+(size_t)m*16, acc);
}

// ---------------- slice ----------------
__global__ void __launch_bounds__(256)
k_slice(const u32* __restrict__ inv, const float* __restrict__ bary,
        const float* __restrict__ val, int N, float* __restrict__ out)
{
  int n=blockIdx.x*256+threadIdx.x;
  if(n>=N) return;
  float acc[16];
#pragma unroll
  for(int k=0;k<16;k++) acc[k]=0.f;
#pragma unroll 1
  for(int r=0;r<6;r++){
    u32 u=inv[(size_t)n*6+r];
    float w=bary[(size_t)n*6+r];
    float t[16]; row_load(val+(size_t)u*16,t);
#pragma unroll
    for(int k=0;k<16;k++) acc[k]+=w*t[k];
  }
  const float alpha=0.9696969696969697f;
  float4* q=(float4*)(out+(size_t)n*16);
#pragma unroll
  for(int i=0;i<4;i++) q[i]=make_float4(alpha*acc[4*i],alpha*acc[4*i+1],alpha*acc[4*i+2],alpha*acc[4*i+3]);
}

__global__ void k_diag(float* out, float v){ out[0]=v; }

// ---------------- host ----------------
extern "C" void kernel_launch(void* const* d_in, const int* in_sizes, int n_in,
                              void* d_out, int out_size, void* d_ws, size_t ws_size,
                              hipStream_t stream)
{
  const float* feat   =(const float*)d_in[0];
  const float* values =(const float*)d_in[1];
  float* out=(float*)d_out;
  int N=in_sizes[0]/5;
  size_t M=(size_t)N*6;

  u32 nb=(u32)((M+CHUNK-1)/CHUNK);          // #chunks in hist/part passes
  size_t K=(size_t)nb*BINS;                  // histogram matrix size
  const u32 QCAP=8192;

  // v1 doubles as scratch: hist[K] histT[K] skey[M] sw[M] bsum[K/1024] q[QCAP] qn
  auto v1bytes=[&](size_t U)->size_t{
    size_t a=U*64;
    size_t b=K*4+K*4+M*4+M*4+(K/1024)*4+QCAP*4+1024;
    return a>b?a:b;
  };
  auto need=[&](int lC,int lU)->size_t{
    size_t C=1ull<<lC, U=1ull<<lU, s=0;
    auto al=[&](size_t b){ s=(s+255)&~(size_t)255; s+=b; };
    al(4); al(M*4); al(M*4); al(C*8); al(C*4); al(U*4); al(U*64); al(v1bytes(U));
    return s+256;
  };
  const int prefs[4][2]={{22,20},{21,20},{21,19},{20,18}};
  int lC=0,lU=0;
  for(int i=0;i<4;i++){ if(need(prefs[i][0],prefs[i][1])<=ws_size){ lC=prefs[i][0]; lU=prefs[i][1]; break; } }
  if(!lC){
    hipMemsetAsync(d_out,0,(size_t)out_size*sizeof(float),stream);
    k_diag<<<1,1,0,stream>>>(out,(float)(ws_size>>20));
    return;
  }

  size_t C=1ull<<lC, Ucap=1ull<<lU; u32 cmask=(u32)(C-1);
  char* base=(char*)d_ws; size_t offb=0;
  auto carve=[&](size_t b)->char*{ offb=(offb+255)&~(size_t)255; char* p=base+offb; offb+=b; return p; };
  u32*   counter=(u32*)carve(4);
  u32*   inv    =(u32*)carve(M*4);
  float* bary   =(float*)carve(M*4);
  u64*   tabk   =(u64*)carve(C*8);
  u32*   tuid   =(u32*)carve(C*4);
  u32*   uidslot=(u32*)carve(Ucap*4);
  float* v0     =(float*)carve(Ucap*64);
  float* v1     =(float*)carve(v1bytes(Ucap));

  u32*   hist =(u32*)v1;
  u32*   histT=hist+K;
  u32*   skey =histT+K;
  float* sw   =(float*)(skey+M);
  u32*   bsum =(u32*)(sw+M);
  u32*   q    =bsum+(K/1024);
  u32*   qn   =q+QCAP;

  hipMemsetAsync(counter,0,4,stream);
  hipMemsetAsync(qn,0,4,stream);
  hipMemsetAsync(tabk,0xFF,C*8,stream);
  hipMemsetAsync(v0,0,Ucap*64,stream);   // zero-init for split-bin atomic flush

  const int B=256;
  k_setup<<<(N+B-1)/B,B,0,stream>>>(feat,N,tabk,cmask,inv,bary);
  k_uid  <<<(u32)((C+B-1)/B),B,0,stream>>>(tabk,(u32)C,(u32)Ucap,tuid,uidslot,counter);

  k_hist <<<nb,B,0,stream>>>(inv,tuid,hist,M);
  {
    dim3 g((BINS+31)/32,(nb+31)/32);
    k_transpose<<<g,B,0,stream>>>(hist,histT,nb,BINS);   // hist[nb][BINS] -> histT[BINS][nb]
  }
  u32 sb=(u32)(K/1024);                                  // K is a multiple of 1024
  k_scan1<<<sb,B,0,stream>>>(histT,bsum);
  k_scan2<<<1 ,B,0,stream>>>(bsum,sb);
  k_scan3<<<sb,B,0,stream>>>(histT,bsum);
  k_part <<<nb,B,0,stream>>>(inv,bary,histT,nb,skey,sw,M);

  k_queue<<<(BINS+B-1)/B,B,0,stream>>>(histT,nb,M,q,qn);

  u32 rows=(u32)(Ucap>>12);
  k_accum<<<QCAP,B,0,stream>>>(q,qn,skey,sw,values,histT,nb,rows,M,v0);

  const long long P[5]={1ll,2048ll,1ll<<22,1ll<<33,1ll<<44};
  const long long SUM=P[0]+P[1]+P[2]+P[3]+P[4];
  u32 gb=(u32)((Ucap+B-1)/B);
  float* a=v0; float* bb=v1;
  for(int j=0;j<6;j++){
    long long delta=(j<5)? (SUM-6*P[4-j]) : SUM;
    k_blur<<<gb,B,0,stream>>>(tabk,tuid,cmask,uidslot,counter,(u32)Ucap,delta,a,bb);
    float* t=a; a=bb; bb=t;
  }
  k_slice<<<(N+B-1)/B,B,0,stream>>>(inv,bary,a,N,out);
}

// Round 7
// 1725.131 us; speedup vs baseline: 1.5828x; 1.0093x over previous
//
#include <hip/hip_runtime.h>
#include <stdint.h>

typedef unsigned long long u64;
typedef unsigned int u32;

static constexpr u64 KEMPTY = ~0ull;
static constexpr int PROBE_CAP = 32768;
static constexpr u32 BINS  = 4096;   // partition on uid & 4095 (hash-uniform)
static constexpr u32 CHUNK = 4096;   // entries per block in hist/part passes
static constexpr u32 SPLIT = 8192;   // max entries per accum work-item

static __device__ __forceinline__ u64 mix64(u64 x){
  x ^= x >> 30; x *= 0xbf58476d1ce4e5b9ull;
  x ^= x >> 27; x *= 0x94d049bb133111ebull;
  x ^= x >> 31; return x;
}

static __device__ __forceinline__ long long lookup_slot(const u64* __restrict__ tk, u32 cmask, u64 code){
  u32 h = (u32)mix64(code) & cmask;
#pragma unroll 1
  for(int p=0;p<PROBE_CAP;p++){
    u64 cur = tk[h];
    if(cur==code) return (long long)h;
    if(cur==KEMPTY) return -1;
    h=(h+1)&cmask;
  }
  return -1;
}

static __device__ __forceinline__ void atomAddF(float* p, float v){
#if defined(__gfx90a__) || defined(__gfx940__) || defined(__gfx941__) || defined(__gfx942__) || defined(__gfx950__)
  unsafeAtomicAdd(p, v);
#else
  atomicAdd(p, v);
#endif
}

static __device__ __forceinline__ void row_load(const float* __restrict__ p, float* o){
  const float4* q=(const float4*)p;
#pragma unroll
  for(int i=0;i<4;i++){ float4 v=q[i]; o[4*i]=v.x; o[4*i+1]=v.y; o[4*i+2]=v.z; o[4*i+3]=v.w; }
}
static __device__ __forceinline__ void row_store(float* __restrict__ p, const float* o){
  float4* q=(float4*)p;
#pragma unroll
  for(int i=0;i<4;i++) q[i]=make_float4(o[4*i],o[4*i+1],o[4*i+2],o[4*i+3]);
}

// ---------------- kernel 1: elevate/rank/bary + table insert; stores SLOT in inv ----------------
__global__ void __launch_bounds__(256)
k_setup(const float* __restrict__ feat, int N,
        u64* __restrict__ tabk, u32 cmask,
        u32* __restrict__ inv_slot, float* __restrict__ bary)
{
#pragma clang fp contract(off)
  int n = blockIdx.x*256 + threadIdx.x;
  if(n>=N) return;

  const float s0=3.4641016151377544f, s1=2.0f, s2=1.4142135623730951f,
              s3=1.0954451150103321f, s4=0.8944271909999159f;
  float c[5];
  c[0]=feat[n*5+0]*s0; c[1]=feat[n*5+1]*s1; c[2]=feat[n*5+2]*s2;
  c[3]=feat[n*5+3]*s3; c[4]=feat[n*5+4]*s4;

  float sfx[6]; sfx[5]=0.f;
#pragma unroll
  for(int i=4;i>=0;i--) sfx[i]=sfx[i+1]+c[i];
  float el[6];
  el[0]=sfx[0];
#pragma unroll
  for(int i=1;i<6;i++) el[i]=sfx[i]-(float)i*c[i-1];

  const float down=1.0f/6.0f;
  float rd[6], rem0[6], rdsum=0.f;
#pragma unroll
  for(int i=0;i<6;i++){ rd[i]=rintf(el[i]*down); rem0[i]=rd[i]*6.0f; rdsum+=rd[i]; }
  int sumi=(int)rdsum;

  float diff[6];
#pragma unroll
  for(int i=0;i<6;i++) diff[i]=(el[i]-rem0[i])*down;

  int rank[6];
#pragma unroll
  for(int i=0;i<6;i++){
    int r=0;
#pragma unroll
    for(int j=0;j<6;j++)
      r += (diff[j]>diff[i]) || (diff[j]==diff[i] && j<i);
    rank[i]=r+sumi;
  }
  int rem0i[6];
#pragma unroll
  for(int i=0;i<6;i++){
    rem0i[i]=(int)rem0[i];
    int sh=(rank[i]<0)-(rank[i]>5);
    rank[i]+=6*sh; rem0i[i]+=6*sh;
  }

  float b[7]={0.f,0.f,0.f,0.f,0.f,0.f,0.f};
#pragma unroll
  for(int i=0;i<6;i++){
    float t=(el[i]-(float)rem0i[i])*down;
    int k0=5-rank[i]; if(k0>=0&&k0<7) b[k0]+=t;
  }
#pragma unroll
  for(int i=0;i<6;i++){
    float t=(el[i]-(float)rem0i[i])*down;
    int k1=6-rank[i]; if(k1>=0&&k1<7) b[k1]-=t;
  }
  bary[(size_t)n*6+0]=(b[0]+1.0f)+b[6];
#pragma unroll
  for(int r=1;r<6;r++) bary[(size_t)n*6+r]=b[r];

#pragma unroll 1
  for(int r=0;r<6;r++){
    long long code=0;
#pragma unroll
    for(int i=0;i<5;i++){
      int key = rem0i[i] + ((rank[i] >= 6-r) ? (r-6) : r);
      code = code*2048 + (long long)(key+1024);
    }
    u32 h=(u32)mix64((u64)code)&cmask;
    u32 slot=0xFFFFFFFFu;
#pragma unroll 1
    for(int p=0;p<PROBE_CAP;p++){
      u64 cur=tabk[h];
      if(cur==(u64)code){ slot=h; break; }
      if(cur==KEMPTY){
        u64 old=atomicCAS((unsigned long long*)&tabk[h], KEMPTY, (u64)code);
        if(old==KEMPTY || old==(u64)code){ slot=h; break; }
      } else {
        h=(h+1)&cmask;
      }
    }
    inv_slot[(size_t)n*6+r]=slot;
  }
}

// ---------------- kernel 2: compact uids ----------------
__global__ void __launch_bounds__(256)
k_uid(const u64* __restrict__ tabk, u32 C, u32 Ucap, u32* __restrict__ tuid,
      u32* __restrict__ uidslot, u32* __restrict__ counter)
{
  u32 s=blockIdx.x*256+threadIdx.x;
  if(s>=C) return;
  if(tabk[s]==KEMPTY) return;
  u32 uid=atomicAdd(counter,1u);
  if(uid<Ucap) uidslot[uid]=s; else uid=0;
  tuid[s]=uid;
}

// ---------------- pass A: slot->uid translation + per-chunk LDS histogram ----------------
__global__ void __launch_bounds__(256)
k_hist(u32* __restrict__ inv, const u32* __restrict__ tuid,
       u32* __restrict__ hist, size_t M)
{
  __shared__ u32 h[BINS];
  u32 t=threadIdx.x, b=blockIdx.x;
#pragma unroll
  for(int j=0;j<(int)(BINS/256);j++) h[t+j*256]=0;
  __syncthreads();
  size_t base=(size_t)b*CHUNK;
#pragma unroll
  for(int j=0;j<(int)(CHUNK/256);j++){
    size_t i=base + (size_t)j*256 + t;
    if(i<M){
      u32 u=tuid[inv[i]];
      inv[i]=u;
      atomicAdd(&h[u&(BINS-1)],1u);
    }
  }
  __syncthreads();
#pragma unroll
  for(int j=0;j<(int)(BINS/256);j++){
    u32 bin=t+j*256;
    hist[(size_t)b*BINS+bin]=h[bin];
  }
}

// ---------------- transpose: in[R][C] -> out[C][R] ----------------
__global__ void __launch_bounds__(256)
k_transpose(const u32* __restrict__ in, u32* __restrict__ out, u32 R, u32 C)
{
  __shared__ u32 tile[32][33];
  u32 bx=blockIdx.x, by=blockIdx.y;
  u32 tx=threadIdx.x&31, ty=threadIdx.x>>5;   // 32 x 8
  u32 c0=bx*32, r0=by*32;
#pragma unroll
  for(u32 j=0;j<32;j+=8){
    u32 r=r0+ty+j, c=c0+tx;
    if(r<R && c<C) tile[ty+j][tx]=in[(size_t)r*C+c];
  }
  __syncthreads();
#pragma unroll
  for(u32 j=0;j<32;j+=8){
    u32 c=c0+ty+j, r=r0+tx;
    if(c<C && r<R) out[(size_t)c*R+r]=tile[tx][ty+j];
  }
}

// ---------------- 3-level exclusive scan over histT (K items, mult of 1024) ----------------
__global__ void __launch_bounds__(256)
k_scan1(const u32* __restrict__ v, u32* __restrict__ bsum)
{
  __shared__ u32 sm[256];
  u32 t=threadIdx.x, b=blockIdx.x;
  size_t base=((size_t)b*256+t)*4;
  u32 s=v[base]+v[base+1]+v[base+2]+v[base+3];
  sm[t]=s; __syncthreads();
  for(int o=128;o>0;o>>=1){ if(t<(u32)o) sm[t]+=sm[t+o]; __syncthreads(); }
  if(t==0) bsum[b]=sm[0];
}

__global__ void __launch_bounds__(256)
k_scan2(u32* __restrict__ bsum, u32 nb)
{
  __shared__ u32 sm[256];
  u32 t=threadIdx.x;
  u32 per=(nb+255)/256;
  u32 lo=t*per, hi=lo+per; if(hi>nb) hi=nb; if(lo>nb) lo=nb;
  u32 tot=0;
  for(u32 i=lo;i<hi;i++) tot+=bsum[i];
  sm[t]=tot; __syncthreads();
  for(int o=1;o<256;o<<=1){
    u32 v=sm[t]; u32 a=(t>=(u32)o)?sm[t-o]:0u; __syncthreads();
    sm[t]=v+a; __syncthreads();
  }
  u32 run=sm[t]-tot;
  for(u32 i=lo;i<hi;i++){ u32 c=bsum[i]; bsum[i]=run; run+=c; }
}

__global__ void __launch_bounds__(256)
k_scan3(u32* __restrict__ v, const u32* __restrict__ bsum)
{
  __shared__ u32 sm[256];
  u32 t=threadIdx.x, b=blockIdx.x;
  size_t base=((size_t)b*256+t)*4;
  u32 c[4]; u32 tot=0;
#pragma unroll
  for(int j=0;j<4;j++){ c[j]=v[base+j]; tot+=c[j]; }
  sm[t]=tot; __syncthreads();
  for(int o=1;o<256;o<<=1){
    u32 x=sm[t]; u32 a=(t>=(u32)o)?sm[t-o]:0u; __syncthreads();
    sm[t]=x+a; __syncthreads();
  }
  u32 run=bsum[b]+sm[t]-tot;
#pragma unroll
  for(int j=0;j<4;j++){ v[base+j]=run; run+=c[j]; }
}

// ---------------- pass C: partition entries into bins (LDS cursors, no global atomics) ----------------
// skey packs (uid>>12)<<20 | point_index  (valid for N <= 2^20, Ucap <= 2^20)
__global__ void __launch_bounds__(256)
k_part(const u32* __restrict__ inv, const float* __restrict__ bary,
       const u32* __restrict__ histT, u32 nb,
       u32* __restrict__ skey, float* __restrict__ sw, size_t M)
{
  __shared__ u32 cur[BINS];
  u32 t=threadIdx.x, b=blockIdx.x;
#pragma unroll
  for(int j=0;j<(int)(BINS/256);j++){
    u32 bin=t+j*256;
    cur[bin]=histT[(size_t)bin*nb+b];
  }
  __syncthreads();
  size_t base=(size_t)b*CHUNK;
#pragma unroll
  for(int j=0;j<(int)(CHUNK/256);j++){
    size_t i=base+(size_t)j*256+t;
    if(i<M){
      u32 u=inv[i];
      u32 pos=atomicAdd(&cur[u&(BINS-1)],1u);
      skey[pos]=((u>>12)<<20)|((u32)(i/6u));
      sw[pos]=bary[i];
    }
  }
}

// ---------------- queue build: split each bin into G=ceil(size/SPLIT) balanced slices ----------------
// q entry: bin[0:12) | g[12:22) | G[22:32)
__global__ void __launch_bounds__(256)
k_queue(const u32* __restrict__ histT, u32 nb, size_t M,
        u32* __restrict__ q, u32* __restrict__ qn)
{
  u32 b=blockIdx.x*256+threadIdx.x;
  if(b>=BINS) return;
  size_t s=histT[(size_t)b*nb];
  size_t e=(b+1<BINS)? (size_t)histT[(size_t)(b+1)*nb] : M;
  u32 sz=(u32)(e-s);
  if(sz==0) return;
  u32 G=(sz+SPLIT-1)/SPLIT; if(G>1023u) G=1023u;
  u32 base=atomicAdd(qn,G);
  for(u32 g=0; g<G; g++) q[base+g] = b | (g<<12) | (G<<22);
}

// ---------------- pass D: per-slice LDS accumulate + flush (8-deep gather pipeline) ----------------
__global__ void __launch_bounds__(256)
k_accum(const u32* __restrict__ q, const u32* __restrict__ qn,
        const u32* __restrict__ skey, const float* __restrict__ sw,
        const float* __restrict__ values, const u32* __restrict__ histT,
        u32 nb, u32 rows, size_t M, float* __restrict__ v0)
{
  __shared__ float acc[4096];           // rows*16 <= 4096 (16 KB)
  u32 j=blockIdx.x;
  if(j>=*qn) return;
  u32 ent=q[j];
  u32 b=ent&4095u, g=(ent>>12)&1023u, G=ent>>22;
  size_t s0=histT[(size_t)b*nb];
  size_t e0=(b+1<BINS)? (size_t)histT[(size_t)(b+1)*nb] : M;
  u32 sz=(u32)(e0-s0);
  u32 chunk=(sz+G-1)/G;
  size_t s=s0+(size_t)g*chunk;
  size_t e=s+chunk; if(e>e0) e=e0;

  u32 t=threadIdx.x;
  u32 tot=rows*16;
  for(u32 x=t;x<tot;x+=256) acc[x]=0.f;
  __syncthreads();

  u32 gr=t>>4, k=t&15;
  size_t base=s;
  // main: 128 entries per block-iteration, 8 independent gather chains per thread
  for(; base+128<=e; base+=128){
    u32   key[8]; float w[8]; float x[8];
#pragma unroll
    for(int u8=0;u8<8;u8++){ size_t ei=base+(size_t)u8*16+gr; key[u8]=skey[ei]; w[u8]=sw[ei]; }
#pragma unroll
    for(int u8=0;u8<8;u8++){ x[u8]=values[(size_t)(key[u8]&0xFFFFFu)*16+k]; }
#pragma unroll
    for(int u8=0;u8<8;u8++) atomicAdd(&acc[(key[u8]>>20)*16+k], w[u8]*x[u8]);
  }
  // tail
  for(; base<e; base+=16){
    size_t ei=base+gr;
    if(ei<e){
      u32 key=skey[ei]; float w=sw[ei];
      float x=values[(size_t)(key&0xFFFFFu)*16+k];
      atomicAdd(&acc[(key>>20)*16+k], w*x);
    }
  }
  __syncthreads();

  if(G==1){
    for(u32 x=t;x<tot;x+=256){
      u32 row=x>>4, kk=x&15;
      v0[(size_t)((row<<12)|b)*16+kk]=acc[x];
    }
  } else {
    for(u32 x=t;x<tot;x+=256){
      float a=acc[x];
      if(a!=0.f){
        u32 row=x>>4, kk=x&15;
        atomAddF(&v0[(size_t)((row<<12)|b)*16+kk], a);
      }
    }
  }
}

// ---------------- blur ----------------
__global__ void __launch_bounds__(256)
k_blur(const u64* __restrict__ tabk, const u32* __restrict__ tuid, u32 cmask,
       const u32* __restrict__ uidslot, const u32* __restrict__ counter, u32 Ucap,
       long long delta, const float* __restrict__ vin, float* __restrict__ vout)
{
  u32 m=blockIdx.x*256+threadIdx.x;
  u32 U=*counter; if(U>Ucap) U=Ucap;
  if(m>=U) return;
  long long code=(long long)tabk[uidslot[m]];
  long long sp=lookup_slot(tabk,cmask,(u64)(code+delta));
  long long sm=lookup_slot(tabk,cmask,(u64)(code-delta));
  float acc[16];
  row_load(vin+(size_t)m*16, acc);
#pragma unroll
  for(int k=0;k<16;k++) acc[k]*=0.5f;
  if(sp>=0){
    u32 u=tuid[sp]; float t[16]; row_load(vin+(size_t)u*16,t);
#pragma unroll
    for(int k=0;k<16;k++) acc[k]+=0.25f*t[k];
  }
  if(sm>=0){
    u32 u=tuid[sm]; float t[16]; row_load(vin+(size_t)u*16,t);
#pragma unroll
    for(int k=0;k<16;k++) acc[k]+=0.25f*t[k];
  }
  row_store(vout+(size_t)m*16, acc);
}

// ---------------- slice: 6 independent row gathers in flight ----------------
__global__ void __launch_bounds__(256)
k_slice(const u32* __restrict__ inv, const float* __restrict__ bary,
        const float* __restrict__ val, int N, float* __restrict__ out)
{
  int n=blockIdx.x*256+threadIdx.x;
  if(n>=N) return;
  u32 u[6]; float w[6];
#pragma unroll
  for(int r=0;r<6;r++){ u[r]=inv[(size_t)n*6+r]; w[r]=bary[(size_t)n*6+r]; }
  float t6[6][16];
#pragma unroll
  for(int r=0;r<6;r++) row_load(val+(size_t)u[r]*16, t6[r]);
  float acc[16];
#pragma unroll
  for(int k=0;k<16;k++){
    float a=w[0]*t6[0][k];
#pragma unroll
    for(int r=1;r<6;r++) a+=w[r]*t6[r][k];
    acc[k]=a;
  }
  const float alpha=0.9696969696969697f;
  float4* q=(float4*)(out+(size_t)n*16);
#pragma unroll
  for(int i=0;i<4;i++) q[i]=make_float4(alpha*acc[4*i],alpha*acc[4*i+1],alpha*acc[4*i+2],alpha*acc[4*i+3]);
}

__global__ void k_diag(float* out, float v){ out[0]=v; }

// ---------------- host ----------------
extern "C" void kernel_launch(void* const* d_in, const int* in_sizes, int n_in,
                              void* d_out, int out_size, void* d_ws, size_t ws_size,
                              hipStream_t stream)
{
  const float* feat   =(const float*)d_in[0];
  const float* values =(const float*)d_in[1];
  float* out=(float*)d_out;
  int N=in_sizes[0]/5;
  size_t M=(size_t)N*6;

  u32 nb=(u32)((M+CHUNK-1)/CHUNK);          // #chunks in hist/part passes
  size_t K=(size_t)nb*BINS;                  // histogram matrix size
  const u32 QCAP=8192;

  // v1 doubles as scratch: hist[K] histT[K] skey[M] sw[M] bsum[K/1024] q[QCAP] qn
  auto v1bytes=[&](size_t U)->size_t{
    size_t a=U*64;
    size_t b=K*4+K*4+M*4+M*4+(K/1024)*4+QCAP*4+1024;
    return a>b?a:b;
  };
  auto need=[&](int lC,int lU)->size_t{
    size_t C=1ull<<lC, U=1ull<<lU, s=0;
    auto al=[&](size_t b){ s=(s+255)&~(size_t)255; s+=b; };
    al(4); al(M*4); al(M*4); al(C*8); al(C*4); al(U*4); al(U*64); al(v1bytes(U));
    return s+256;
  };
  const int prefs[4][2]={{22,20},{21,20},{21,19},{20,18}};
  int lC=0,lU=0;
  for(int i=0;i<4;i++){ if(need(prefs[i][0],prefs[i][1])<=ws_size){ lC=prefs[i][0]; lU=prefs[i][1]; break; } }
  if(!lC){
    hipMemsetAsync(d_out,0,(size_t)out_size*sizeof(float),stream);
    k_diag<<<1,1,0,stream>>>(out,(float)(ws_size>>20));
    return;
  }

  size_t C=1ull<<lC, Ucap=1ull<<lU; u32 cmask=(u32)(C-1);
  char* base=(char*)d_ws; size_t offb=0;
  auto carve=[&](size_t b)->char*{ offb=(offb+255)&~(size_t)255; char* p=base+offb; offb+=b; return p; };
  u32*   counter=(u32*)carve(4);
  u32*   inv    =(u32*)carve(M*4);
  float* bary   =(float*)carve(M*4);
  u64*   tabk   =(u64*)carve(C*8);
  u32*   tuid   =(u32*)carve(C*4);
  u32*   uidslot=(u32*)carve(Ucap*4);
  float* v0     =(float*)carve(Ucap*64);
  float* v1     =(float*)carve(v1bytes(Ucap));

  u32*   hist =(u32*)v1;
  u32*   histT=hist+K;
  u32*   skey =histT+K;
  float* sw   =(float*)(skey+M);
  u32*   bsum =(u32*)(sw+M);
  u32*   q    =bsum+(K/1024);
  u32*   qn   =q+QCAP;

  hipMemsetAsync(counter,0,4,stream);
  hipMemsetAsync(qn,0,4,stream);
  hipMemsetAsync(tabk,0xFF,C*8,stream);
  hipMemsetAsync(v0,0,Ucap*64,stream);   // zero-init for split-bin atomic flush

  const int B=256;
  k_setup<<<(N+B-1)/B,B,0,stream>>>(feat,N,tabk,cmask,inv,bary);
  k_uid  <<<(u32)((C+B-1)/B),B,0,stream>>>(tabk,(u32)C,(u32)Ucap,tuid,uidslot,counter);

  k_hist <<<nb,B,0,stream>>>(inv,tuid,hist,M);
  {
    dim3 g((BINS+31)/32,(nb+31)/32);
    k_transpose<<<g,B,0,stream>>>(hist,histT,nb,BINS);   // hist[nb][BINS] -> histT[BINS][nb]
  }
  u32 sb=(u32)(K/1024);                                  // K is a multiple of 1024
  k_scan1<<<sb,B,0,stream>>>(histT,bsum);
  k_scan2<<<1 ,B,0,stream>>>(bsum,sb);
  k_scan3<<<sb,B,0,stream>>>(histT,bsum);
  k_part <<<nb,B,0,stream>>>(inv,bary,histT,nb,skey,sw,M);

  k_queue<<<(BINS+B-1)/B,B,0,stream>>>(histT,nb,M,q,qn);

  u32 rows=(u32)(Ucap>>12);
  k_accum<<<QCAP,B,0,stream>>>(q,qn,skey,sw,values,histT,nb,rows,M,v0);

  const long long P[5]={1ll,2048ll,1ll<<22,1ll<<33,1ll<<44};
  const long long SUM=P[0]+P[1]+P[2]+P[3]+P[4];
  u32 gb=(u32)((Ucap+B-1)/B);
  float* a=v0; float* bb=v1;
  for(int j=0;j<6;j++){
    long long delta=(j<5)? (SUM-6*P[4-j]) : SUM;
    k_blur<<<gb,B,0,stream>>>(tabk,tuid,cmask,uidslot,counter,(u32)Ucap,delta,a,bb);
    float* t=a; a=bb; bb=t;
  }
  k_slice<<<(N+B-1)/B,B,0,stream>>>(inv,bary,a,N,out);
}

// Round 8
// 1426.649 us; speedup vs baseline: 1.9140x; 1.2092x over previous
//
#include <hip/hip_runtime.h>
#include <stdint.h>

typedef unsigned long long u64;
typedef unsigned int u32;

static constexpr u64 KEMPTY = ~0ull;
static constexpr int PROBE_CAP = 32768;
static constexpr u32 BINS  = 4096;   // partition on uid & 4095 (hash-uniform)
static constexpr u32 CHUNK = 4096;   // entries per block in hist/part passes
static constexpr u32 SPLIT = 2048;   // max entries per accum work-item (tail control)

static __device__ __forceinline__ u64 mix64(u64 x){
  x ^= x >> 30; x *= 0xbf58476d1ce4e5b9ull;
  x ^= x >> 27; x *= 0x94d049bb133111ebull;
  x ^= x >> 31; return x;
}

static __device__ __forceinline__ long long lookup_slot(const u64* __restrict__ tk, u32 cmask, u64 code){
  u32 h = (u32)mix64(code) & cmask;
#pragma unroll 1
  for(int p=0;p<PROBE_CAP;p++){
    u64 cur = tk[h];
    if(cur==code) return (long long)h;
    if(cur==KEMPTY) return -1;
    h=(h+1)&cmask;
  }
  return -1;
}

static __device__ __forceinline__ void atomAddF(float* p, float v){
#if defined(__gfx90a__) || defined(__gfx940__) || defined(__gfx941__) || defined(__gfx942__) || defined(__gfx950__)
  unsafeAtomicAdd(p, v);
#else
  atomicAdd(p, v);
#endif
}

static __device__ __forceinline__ void row_load(const float* __restrict__ p, float* o){
  const float4* q=(const float4*)p;
#pragma unroll
  for(int i=0;i<4;i++){ float4 v=q[i]; o[4*i]=v.x; o[4*i+1]=v.y; o[4*i+2]=v.z; o[4*i+3]=v.w; }
}
static __device__ __forceinline__ void row_store(float* __restrict__ p, const float* o){
  float4* q=(float4*)p;
#pragma unroll
  for(int i=0;i<4;i++) q[i]=make_float4(o[4*i],o[4*i+1],o[4*i+2],o[4*i+3]);
}

// ---------------- kernel 1: elevate/rank/bary + table insert; stores SLOT in inv ----------------
__global__ void __launch_bounds__(256)
k_setup(const float* __restrict__ feat, int N,
        u64* __restrict__ tabk, u32 cmask,
        u32* __restrict__ inv_slot, float* __restrict__ bary)
{
#pragma clang fp contract(off)
  int n = blockIdx.x*256 + threadIdx.x;
  if(n>=N) return;

  const float s0=3.4641016151377544f, s1=2.0f, s2=1.4142135623730951f,
              s3=1.0954451150103321f, s4=0.8944271909999159f;
  float c[5];
  c[0]=feat[n*5+0]*s0; c[1]=feat[n*5+1]*s1; c[2]=feat[n*5+2]*s2;
  c[3]=feat[n*5+3]*s3; c[4]=feat[n*5+4]*s4;

  float sfx[6]; sfx[5]=0.f;
#pragma unroll
  for(int i=4;i>=0;i--) sfx[i]=sfx[i+1]+c[i];
  float el[6];
  el[0]=sfx[0];
#pragma unroll
  for(int i=1;i<6;i++) el[i]=sfx[i]-(float)i*c[i-1];

  const float down=1.0f/6.0f;
  float rd[6], rem0[6], rdsum=0.f;
#pragma unroll
  for(int i=0;i<6;i++){ rd[i]=rintf(el[i]*down); rem0[i]=rd[i]*6.0f; rdsum+=rd[i]; }
  int sumi=(int)rdsum;

  float diff[6];
#pragma unroll
  for(int i=0;i<6;i++) diff[i]=(el[i]-rem0[i])*down;

  int rank[6];
#pragma unroll
  for(int i=0;i<6;i++){
    int r=0;
#pragma unroll
    for(int j=0;j<6;j++)
      r += (diff[j]>diff[i]) || (diff[j]==diff[i] && j<i);
    rank[i]=r+sumi;
  }
  int rem0i[6];
#pragma unroll
  for(int i=0;i<6;i++){
    rem0i[i]=(int)rem0[i];
    int sh=(rank[i]<0)-(rank[i]>5);
    rank[i]+=6*sh; rem0i[i]+=6*sh;
  }

  float b[7]={0.f,0.f,0.f,0.f,0.f,0.f,0.f};
#pragma unroll
  for(int i=0;i<6;i++){
    float t=(el[i]-(float)rem0i[i])*down;
    int k0=5-rank[i]; if(k0>=0&&k0<7) b[k0]+=t;
  }
#pragma unroll
  for(int i=0;i<6;i++){
    float t=(el[i]-(float)rem0i[i])*down;
    int k1=6-rank[i]; if(k1>=0&&k1<7) b[k1]-=t;
  }
  bary[(size_t)n*6+0]=(b[0]+1.0f)+b[6];
#pragma unroll
  for(int r=1;r<6;r++) bary[(size_t)n*6+r]=b[r];

#pragma unroll 1
  for(int r=0;r<6;r++){
    long long code=0;
#pragma unroll
    for(int i=0;i<5;i++){
      int key = rem0i[i] + ((rank[i] >= 6-r) ? (r-6) : r);
      code = code*2048 + (long long)(key+1024);
    }
    u32 h=(u32)mix64((u64)code)&cmask;
    u32 slot=0xFFFFFFFFu;
#pragma unroll 1
    for(int p=0;p<PROBE_CAP;p++){
      u64 cur=tabk[h];
      if(cur==(u64)code){ slot=h; break; }
      if(cur==KEMPTY){
        u64 old=atomicCAS((unsigned long long*)&tabk[h], KEMPTY, (u64)code);
        if(old==KEMPTY || old==(u64)code){ slot=h; break; }
      } else {
        h=(h+1)&cmask;
      }
    }
    inv_slot[(size_t)n*6+r]=slot;
  }
}

// ---------------- kernel 2: compact uids ----------------
__global__ void __launch_bounds__(256)
k_uid(const u64* __restrict__ tabk, u32 C, u32 Ucap, u32* __restrict__ tuid,
      u32* __restrict__ uidslot, u32* __restrict__ counter)
{
  u32 s=blockIdx.x*256+threadIdx.x;
  if(s>=C) return;
  if(tabk[s]==KEMPTY) return;
  u32 uid=atomicAdd(counter,1u);
  if(uid<Ucap) uidslot[uid]=s; else uid=0;
  tuid[s]=uid;
}

// ---------------- pass A: slot->uid translation + per-chunk LDS histogram ----------------
__global__ void __launch_bounds__(256)
k_hist(u32* __restrict__ inv, const u32* __restrict__ tuid,
       u32* __restrict__ hist, size_t M)
{
  __shared__ u32 h[BINS];
  u32 t=threadIdx.x, b=blockIdx.x;
#pragma unroll
  for(int j=0;j<(int)(BINS/256);j++) h[t+j*256]=0;
  __syncthreads();
  size_t base=(size_t)b*CHUNK;
#pragma unroll
  for(int j=0;j<(int)(CHUNK/256);j++){
    size_t i=base + (size_t)j*256 + t;
    if(i<M){
      u32 u=tuid[inv[i]];
      inv[i]=u;
      atomicAdd(&h[u&(BINS-1)],1u);
    }
  }
  __syncthreads();
#pragma unroll
  for(int j=0;j<(int)(BINS/256);j++){
    u32 bin=t+j*256;
    hist[(size_t)b*BINS+bin]=h[bin];
  }
}

// ---------------- transpose: in[R][C] -> out[C][R] ----------------
__global__ void __launch_bounds__(256)
k_transpose(const u32* __restrict__ in, u32* __restrict__ out, u32 R, u32 C)
{
  __shared__ u32 tile[32][33];
  u32 bx=blockIdx.x, by=blockIdx.y;
  u32 tx=threadIdx.x&31, ty=threadIdx.x>>5;   // 32 x 8
  u32 c0=bx*32, r0=by*32;
#pragma unroll
  for(u32 j=0;j<32;j+=8){
    u32 r=r0+ty+j, c=c0+tx;
    if(r<R && c<C) tile[ty+j][tx]=in[(size_t)r*C+c];
  }
  __syncthreads();
#pragma unroll
  for(u32 j=0;j<32;j+=8){
    u32 c=c0+ty+j, r=r0+tx;
    if(c<C && r<R) out[(size_t)c*R+r]=tile[tx][ty+j];
  }
}

// ---------------- 3-level exclusive scan over histT (K items, mult of 1024) ----------------
__global__ void __launch_bounds__(256)
k_scan1(const u32* __restrict__ v, u32* __restrict__ bsum)
{
  __shared__ u32 sm[256];
  u32 t=threadIdx.x, b=blockIdx.x;
  size_t base=((size_t)b*256+t)*4;
  u32 s=v[base]+v[base+1]+v[base+2]+v[base+3];
  sm[t]=s; __syncthreads();
  for(int o=128;o>0;o>>=1){ if(t<(u32)o) sm[t]+=sm[t+o]; __syncthreads(); }
  if(t==0) bsum[b]=sm[0];
}

__global__ void __launch_bounds__(256)
k_scan2(u32* __restrict__ bsum, u32 nb)
{
  __shared__ u32 sm[256];
  u32 t=threadIdx.x;
  u32 per=(nb+255)/256;
  u32 lo=t*per, hi=lo+per; if(hi>nb) hi=nb; if(lo>nb) lo=nb;
  u32 tot=0;
  for(u32 i=lo;i<hi;i++) tot+=bsum[i];
  sm[t]=tot; __syncthreads();
  for(int o=1;o<256;o<<=1){
    u32 v=sm[t]; u32 a=(t>=(u32)o)?sm[t-o]:0u; __syncthreads();
    sm[t]=v+a; __syncthreads();
  }
  u32 run=sm[t]-tot;
  for(u32 i=lo;i<hi;i++){ u32 c=bsum[i]; bsum[i]=run; run+=c; }
}

__global__ void __launch_bounds__(256)
k_scan3(u32* __restrict__ v, const u32* __restrict__ bsum)
{
  __shared__ u32 sm[256];
  u32 t=threadIdx.x, b=blockIdx.x;
  size_t base=((size_t)b*256+t)*4;
  u32 c[4]; u32 tot=0;
#pragma unroll
  for(int j=0;j<4;j++){ c[j]=v[base+j]; tot+=c[j]; }
  sm[t]=tot; __syncthreads();
  for(int o=1;o<256;o<<=1){
    u32 x=sm[t]; u32 a=(t>=(u32)o)?sm[t-o]:0u; __syncthreads();
    sm[t]=x+a; __syncthreads();
  }
  u32 run=bsum[b]+sm[t]-tot;
#pragma unroll
  for(int j=0;j<4;j++){ v[base+j]=run; run+=c[j]; }
}

// ---------------- pass C: partition entries into bins (LDS cursors, no global atomics) ----------------
// skey packs (uid>>12)<<20 | point_index  (valid for N <= 2^20, Ucap <= 2^20)
__global__ void __launch_bounds__(256)
k_part(const u32* __restrict__ inv, const float* __restrict__ bary,
       const u32* __restrict__ histT, u32 nb,
       u32* __restrict__ skey, float* __restrict__ sw, size_t M)
{
  __shared__ u32 cur[BINS];
  u32 t=threadIdx.x, b=blockIdx.x;
#pragma unroll
  for(int j=0;j<(int)(BINS/256);j++){
    u32 bin=t+j*256;
    cur[bin]=histT[(size_t)bin*nb+b];
  }
  __syncthreads();
  size_t base=(size_t)b*CHUNK;
#pragma unroll
  for(int j=0;j<(int)(CHUNK/256);j++){
    size_t i=base+(size_t)j*256+t;
    if(i<M){
      u32 u=inv[i];
      u32 pos=atomicAdd(&cur[u&(BINS-1)],1u);
      skey[pos]=((u>>12)<<20)|((u32)(i/6u));
      sw[pos]=bary[i];
    }
  }
}

// ---------------- queue build: split each bin into G=ceil(size/SPLIT) balanced slices ----------------
// q entry: bin[0:12) | g[12:22) | G[22:32)
__global__ void __launch_bounds__(256)
k_queue(const u32* __restrict__ histT, u32 nb, size_t M,
        u32* __restrict__ q, u32* __restrict__ qn)
{
  u32 b=blockIdx.x*256+threadIdx.x;
  if(b>=BINS) return;
  size_t s=histT[(size_t)b*nb];
  size_t e=(b+1<BINS)? (size_t)histT[(size_t)(b+1)*nb] : M;
  u32 sz=(u32)(e-s);
  if(sz==0) return;
  u32 G=(sz+SPLIT-1)/SPLIT; if(G>1023u) G=1023u;
  u32 base=atomicAdd(qn,G);
  for(u32 g=0; g<G; g++) q[base+g] = b | (g<<12) | (G<<22);
}

// ---------------- pass D: per-slice LDS accumulate + flush ----------------
// LDS row stride 17 floats: bank = (17*row + k) % 32 spreads uniformly for fixed k.
__global__ void __launch_bounds__(256)
k_accum(const u32* __restrict__ q, const u32* __restrict__ qn,
        const u32* __restrict__ skey, const float* __restrict__ sw,
        const float* __restrict__ values, const u32* __restrict__ histT,
        u32 nb, u32 rows, size_t M, float* __restrict__ v0)
{
  __shared__ float acc[4352];           // rows(<=256) * 17 floats (17 KB)
  u32 j=blockIdx.x;
  if(j>=*qn) return;
  u32 ent=q[j];
  u32 b=ent&4095u, g=(ent>>12)&1023u, G=ent>>22;
  size_t s0=histT[(size_t)b*nb];
  size_t e0=(b+1<BINS)? (size_t)histT[(size_t)(b+1)*nb] : M;
  u32 sz=(u32)(e0-s0);
  u32 chunk=(sz+G-1)/G;
  size_t s=s0+(size_t)g*chunk;
  size_t e=s+chunk; if(e>e0) e=e0;

  u32 t=threadIdx.x;
  for(u32 x=t;x<rows*17;x+=256) acc[x]=0.f;
  __syncthreads();

  if(G==1){
    // lane-per-entry (slice-shaped): each lane owns one entry, loads the full
    // 64B values row with 4x dwordx4 -> 64 distinct lines in flight per wave-instr.
    size_t base=s;
    for(; base+512<=e; base+=512){
      size_t i0=base+t, i1=base+256+t;
      u32 key0=skey[i0], key1=skey[i1];
      float w0=sw[i0], w1=sw[i1];
      float r0[16], r1[16];
      row_load(values+(size_t)(key0&0xFFFFFu)*16, r0);
      row_load(values+(size_t)(key1&0xFFFFFu)*16, r1);
      u32 a0=(key0>>20)*17, a1=(key1>>20)*17;
#pragma unroll
      for(int k=0;k<16;k++) atomicAdd(&acc[a0+k], w0*r0[k]);
#pragma unroll
      for(int k=0;k<16;k++) atomicAdd(&acc[a1+k], w1*r1[k]);
    }
    for(; base<e; base+=256){
      size_t ei=base+t;
      if(ei<e){
        u32 key=skey[ei]; float w=sw[ei];
        float r[16];
        row_load(values+(size_t)(key&0xFFFFFu)*16, r);
        u32 a=(key>>20)*17;
#pragma unroll
        for(int k=0;k<16;k++) atomicAdd(&acc[a+k], w*r[k]);
      }
    }
  } else {
    // cooperative 16-lane path for hot (split) bins: same-uid entries dominate,
    // lane-per-entry would be a 64-way same-address LDS pileup; this is 4-way.
    u32 gr=t>>4, k=t&15;
    size_t base=s;
    for(; base+128<=e; base+=128){
      u32 key[8]; float w[8]; float x[8];
#pragma unroll
      for(int u8=0;u8<8;u8++){ size_t ei=base+(size_t)u8*16+gr; key[u8]=skey[ei]; w[u8]=sw[ei]; }
#pragma unroll
      for(int u8=0;u8<8;u8++){ x[u8]=values[(size_t)(key[u8]&0xFFFFFu)*16+k]; }
#pragma unroll
      for(int u8=0;u8<8;u8++) atomicAdd(&acc[(key[u8]>>20)*17+k], w[u8]*x[u8]);
    }
    for(; base<e; base+=16){
      size_t ei=base+gr;
      if(ei<e){
        u32 key=skey[ei]; float w=sw[ei];
        float x=values[(size_t)(key&0xFFFFFu)*16+k];
        atomicAdd(&acc[(key>>20)*17+k], w*x);
      }
    }
  }
  __syncthreads();

  if(G==1){
    for(u32 x=t;x<rows*16;x+=256){
      u32 row=x>>4, kk=x&15;
      v0[(size_t)((row<<12)|b)*16+kk]=acc[row*17+kk];
    }
  } else {
    for(u32 x=t;x<rows*16;x+=256){
      u32 row=x>>4, kk=x&15;
      float a=acc[row*17+kk];
      if(a!=0.f) atomAddF(&v0[(size_t)((row<<12)|b)*16+kk], a);
    }
  }
}

// ---------------- blur ----------------
__global__ void __launch_bounds__(256)
k_blur(const u64* __restrict__ tabk, const u32* __restrict__ tuid, u32 cmask,
       const u32* __restrict__ uidslot, const u32* __restrict__ counter, u32 Ucap,
       long long delta, const float* __restrict__ vin, float* __restrict__ vout)
{
  u32 m=blockIdx.x*256+threadIdx.x;
  u32 U=*counter; if(U>Ucap) U=Ucap;
  if(m>=U) return;
  long long code=(long long)tabk[uidslot[m]];
  long long sp=lookup_slot(tabk,cmask,(u64)(code+delta));
  long long sm=lookup_slot(tabk,cmask,(u64)(code-delta));
  float acc[16];
  row_load(vin+(size_t)m*16, acc);
#pragma unroll
  for(int k=0;k<16;k++) acc[k]*=0.5f;
  if(sp>=0){
    u32 u=tuid[sp]; float t[16]; row_load(vin+(size_t)u*16,t);
#pragma unroll
    for(int k=0;k<16;k++) acc[k]+=0.25f*t[k];
  }
  if(sm>=0){
    u32 u=tuid[sm]; float t[16]; row_load(vin+(size_t)u*16,t);
#pragma unroll
    for(int k=0;k<16;k++) acc[k]+=0.25f*t[k];
  }
  row_store(vout+(size_t)m*16, acc);
}

// ---------------- slice: 6 independent row gathers in flight ----------------
__global__ void __launch_bounds__(256)
k_slice(const u32* __restrict__ inv, const float* __restrict__ bary,
        const float* __restrict__ val, int N, float* __restrict__ out)
{
  int n=blockIdx.x*256+threadIdx.x;
  if(n>=N) return;
  u32 u[6]; float w[6];
#pragma unroll
  for(int r=0;r<6;r++){ u[r]=inv[(size_t)n*6+r]; w[r]=bary[(size_t)n*6+r]; }
  float t6[6][16];
#pragma unroll
  for(int r=0;r<6;r++) row_load(val+(size_t)u[r]*16, t6[r]);
  float acc[16];
#pragma unroll
  for(int k=0;k<16;k++){
    float a=w[0]*t6[0][k];
#pragma unroll
    for(int r=1;r<6;r++) a+=w[r]*t6[r][k];
    acc[k]=a;
  }
  const float alpha=0.9696969696969697f;
  float4* q=(float4*)(out+(size_t)n*16);
#pragma unroll
  for(int i=0;i<4;i++) q[i]=make_float4(alpha*acc[4*i],alpha*acc[4*i+1],alpha*acc[4*i+2],alpha*acc[4*i+3]);
}

__global__ void k_diag(float* out, float v){ out[0]=v; }

// ---------------- host ----------------
extern "C" void kernel_launch(void* const* d_in, const int* in_sizes, int n_in,
                              void* d_out, int out_size, void* d_ws, size_t ws_size,
                              hipStream_t stream)
{
  const float* feat   =(const float*)d_in[0];
  const float* values =(const float*)d_in[1];
  float* out=(float*)d_out;
  int N=in_sizes[0]/5;
  size_t M=(size_t)N*6;

  u32 nb=(u32)((M+CHUNK-1)/CHUNK);          // #chunks in hist/part passes
  size_t K=(size_t)nb*BINS;                  // histogram matrix size
  const u32 QCAP=16384;

  // v1 doubles as scratch: hist[K] histT[K] skey[M] sw[M] bsum[K/1024] q[QCAP] qn
  auto v1bytes=[&](size_t U)->size_t{
    size_t a=U*64;
    size_t b=K*4+K*4+M*4+M*4+(K/1024)*4+QCAP*4+1024;
    return a>b?a:b;
  };
  auto need=[&](int lC,int lU)->size_t{
    size_t C=1ull<<lC, U=1ull<<lU, s=0;
    auto al=[&](size_t b){ s=(s+255)&~(size_t)255; s+=b; };
    al(4); al(M*4); al(M*4); al(C*8); al(C*4); al(U*4); al(U*64); al(v1bytes(U));
    return s+256;
  };
  const int prefs[4][2]={{22,20},{21,20},{21,19},{20,18}};
  int lC=0,lU=0;
  for(int i=0;i<4;i++){ if(need(prefs[i][0],prefs[i][1])<=ws_size){ lC=prefs[i][0]; lU=prefs[i][1]; break; } }
  if(!lC){
    hipMemsetAsync(d_out,0,(size_t)out_size*sizeof(float),stream);
    k_diag<<<1,1,0,stream>>>(out,(float)(ws_size>>20));
    return;
  }

  size_t C=1ull<<lC, Ucap=1ull<<lU; u32 cmask=(u32)(C-1);
  char* base=(char*)d_ws; size_t offb=0;
  auto carve=[&](size_t b)->char*{ offb=(offb+255)&~(size_t)255; char* p=base+offb; offb+=b; return p; };
  u32*   counter=(u32*)carve(4);
  u32*   inv    =(u32*)carve(M*4);
  float* bary   =(float*)carve(M*4);
  u64*   tabk   =(u64*)carve(C*8);
  u32*   tuid   =(u32*)carve(C*4);
  u32*   uidslot=(u32*)carve(Ucap*4);
  float* v0     =(float*)carve(Ucap*64);
  float* v1     =(float*)carve(v1bytes(Ucap));

  u32*   hist =(u32*)v1;
  u32*   histT=hist+K;
  u32*   skey =histT+K;
  float* sw   =(float*)(skey+M);
  u32*   bsum =(u32*)(sw+M);
  u32*   q    =bsum+(K/1024);
  u32*   qn   =q+QCAP;

  hipMemsetAsync(counter,0,4,stream);
  hipMemsetAsync(qn,0,4,stream);
  hipMemsetAsync(tabk,0xFF,C*8,stream);
  hipMemsetAsync(v0,0,Ucap*64,stream);   // zero-init for split-bin atomic flush

  const int B=256;
  k_setup<<<(N+B-1)/B,B,0,stream>>>(feat,N,tabk,cmask,inv,bary);
  k_uid  <<<(u32)((C+B-1)/B),B,0,stream>>>(tabk,(u32)C,(u32)Ucap,tuid,uidslot,counter);

  k_hist <<<nb,B,0,stream>>>(inv,tuid,hist,M);
  {
    dim3 g((BINS+31)/32,(nb+31)/32);
    k_transpose<<<g,B,0,stream>>>(hist,histT,nb,BINS);   // hist[nb][BINS] -> histT[BINS][nb]
  }
  u32 sb=(u32)(K/1024);                                  // K is a multiple of 1024
  k_scan1<<<sb,B,0,stream>>>(histT,bsum);
  k_scan2<<<1 ,B,0,stream>>>(bsum,sb);
  k_scan3<<<sb,B,0,stream>>>(histT,bsum);
  k_part <<<nb,B,0,stream>>>(inv,bary,histT,nb,skey,sw,M);

  k_queue<<<(BINS+B-1)/B,B,0,stream>>>(histT,nb,M,q,qn);

  u32 rows=(u32)(Ucap>>12);
  k_accum<<<QCAP,B,0,stream>>>(q,qn,skey,sw,values,histT,nb,rows,M,v0);

  const long long P[5]={1ll,2048ll,1ll<<22,1ll<<33,1ll<<44};
  const long long SUM=P[0]+P[1]+P[2]+P[3]+P[4];
  u32 gb=(u32)((Ucap+B-1)/B);
  float* a=v0; float* bb=v1;
  for(int j=0;j<6;j++){
    long long delta=(j<5)? (SUM-6*P[4-j]) : SUM;
    k_blur<<<gb,B,0,stream>>>(tabk,tuid,cmask,uidslot,counter,(u32)Ucap,delta,a,bb);
    float* t=a; a=bb; bb=t;
  }
  k_slice<<<(N+B-1)/B,B,0,stream>>>(inv,bary,a,N,out);
}

// Round 9
// 1421.643 us; speedup vs baseline: 1.9207x; 1.0035x over previous
//
#include <hip/hip_runtime.h>
#include <stdint.h>

typedef unsigned long long u64;
typedef unsigned int u32;

static constexpr u64 KEMPTY = ~0ull;
static constexpr int PROBE_CAP = 32768;
static constexpr u32 BINS  = 4096;   // partition on uid & 4095 (hash-uniform)
static constexpr u32 CHUNK = 4096;   // entries per block in hist/part passes
static constexpr u32 SPLIT = 2048;   // max entries per accum work-item (tail control)

static __device__ __forceinline__ u64 mix64(u64 x){
  x ^= x >> 30; x *= 0xbf58476d1ce4e5b9ull;
  x ^= x >> 27; x *= 0x94d049bb133111ebull;
  x ^= x >> 31; return x;
}

static __device__ __forceinline__ long long lookup_slot(const u64* __restrict__ tk, u32 cmask, u64 code){
  u32 h = (u32)mix64(code) & cmask;
#pragma unroll 1
  for(int p=0;p<PROBE_CAP;p++){
    u64 cur = tk[h];
    if(cur==code) return (long long)h;
    if(cur==KEMPTY) return -1;
    h=(h+1)&cmask;
  }
  return -1;
}

static __device__ __forceinline__ void atomAddF(float* p, float v){
#if defined(__gfx90a__) || defined(__gfx940__) || defined(__gfx941__) || defined(__gfx942__) || defined(__gfx950__)
  unsafeAtomicAdd(p, v);
#else
  atomicAdd(p, v);
#endif
}

// relaxed workgroup-scope LDS float add: no ordering fence, lets the compiler
// keep global loads of later entries in flight across earlier LDS atomics.
static __device__ __forceinline__ void lds_add(float* p, float v){
  __hip_atomic_fetch_add(p, v, __ATOMIC_RELAXED, __HIP_MEMORY_SCOPE_WORKGROUP);
}
static __device__ __forceinline__ void lds_addu(u32* p, u32 v){
  __hip_atomic_fetch_add(p, v, __ATOMIC_RELAXED, __HIP_MEMORY_SCOPE_WORKGROUP);
}
static __device__ __forceinline__ u32 lds_addu_rtn(u32* p, u32 v){
  return __hip_atomic_fetch_add(p, v, __ATOMIC_RELAXED, __HIP_MEMORY_SCOPE_WORKGROUP);
}

static __device__ __forceinline__ void row_load(const float* __restrict__ p, float* o){
  const float4* q=(const float4*)p;
#pragma unroll
  for(int i=0;i<4;i++){ float4 v=q[i]; o[4*i]=v.x; o[4*i+1]=v.y; o[4*i+2]=v.z; o[4*i+3]=v.w; }
}
static __device__ __forceinline__ void row_store(float* __restrict__ p, const float* o){
  float4* q=(float4*)p;
#pragma unroll
  for(int i=0;i<4;i++) q[i]=make_float4(o[4*i],o[4*i+1],o[4*i+2],o[4*i+3]);
}

// ---------------- kernel 1: elevate/rank/bary + table insert; stores SLOT in inv ----------------
__global__ void __launch_bounds__(256)
k_setup(const float* __restrict__ feat, int N,
        u64* __restrict__ tabk, u32 cmask,
        u32* __restrict__ inv_slot, float* __restrict__ bary)
{
#pragma clang fp contract(off)
  int n = blockIdx.x*256 + threadIdx.x;
  if(n>=N) return;

  const float s0=3.4641016151377544f, s1=2.0f, s2=1.4142135623730951f,
              s3=1.0954451150103321f, s4=0.8944271909999159f;
  float c[5];
  c[0]=feat[n*5+0]*s0; c[1]=feat[n*5+1]*s1; c[2]=feat[n*5+2]*s2;
  c[3]=feat[n*5+3]*s3; c[4]=feat[n*5+4]*s4;

  float sfx[6]; sfx[5]=0.f;
#pragma unroll
  for(int i=4;i>=0;i--) sfx[i]=sfx[i+1]+c[i];
  float el[6];
  el[0]=sfx[0];
#pragma unroll
  for(int i=1;i<6;i++) el[i]=sfx[i]-(float)i*c[i-1];

  const float down=1.0f/6.0f;
  float rd[6], rem0[6], rdsum=0.f;
#pragma unroll
  for(int i=0;i<6;i++){ rd[i]=rintf(el[i]*down); rem0[i]=rd[i]*6.0f; rdsum+=rd[i]; }
  int sumi=(int)rdsum;

  float diff[6];
#pragma unroll
  for(int i=0;i<6;i++) diff[i]=(el[i]-rem0[i])*down;

  int rank[6];
#pragma unroll
  for(int i=0;i<6;i++){
    int r=0;
#pragma unroll
    for(int j=0;j<6;j++)
      r += (diff[j]>diff[i]) || (diff[j]==diff[i] && j<i);
    rank[i]=r+sumi;
  }
  int rem0i[6];
#pragma unroll
  for(int i=0;i<6;i++){
    rem0i[i]=(int)rem0[i];
    int sh=(rank[i]<0)-(rank[i]>5);
    rank[i]+=6*sh; rem0i[i]+=6*sh;
  }

  float b[7]={0.f,0.f,0.f,0.f,0.f,0.f,0.f};
#pragma unroll
  for(int i=0;i<6;i++){
    float t=(el[i]-(float)rem0i[i])*down;
    int k0=5-rank[i]; if(k0>=0&&k0<7) b[k0]+=t;
  }
#pragma unroll
  for(int i=0;i<6;i++){
    float t=(el[i]-(float)rem0i[i])*down;
    int k1=6-rank[i]; if(k1>=0&&k1<7) b[k1]-=t;
  }
  bary[(size_t)n*6+0]=(b[0]+1.0f)+b[6];
#pragma unroll
  for(int r=1;r<6;r++) bary[(size_t)n*6+r]=b[r];

#pragma unroll 1
  for(int r=0;r<6;r++){
    long long code=0;
#pragma unroll
    for(int i=0;i<5;i++){
      int key = rem0i[i] + ((rank[i] >= 6-r) ? (r-6) : r);
      code = code*2048 + (long long)(key+1024);
    }
    u32 h=(u32)mix64((u64)code)&cmask;
    u32 slot=0xFFFFFFFFu;
#pragma unroll 1
    for(int p=0;p<PROBE_CAP;p++){
      u64 cur=tabk[h];
      if(cur==(u64)code){ slot=h; break; }
      if(cur==KEMPTY){
        u64 old=atomicCAS((unsigned long long*)&tabk[h], KEMPTY, (u64)code);
        if(old==KEMPTY || old==(u64)code){ slot=h; break; }
      } else {
        h=(h+1)&cmask;
      }
    }
    inv_slot[(size_t)n*6+r]=slot;
  }
}

// ---------------- kernel 2: compact uids ----------------
__global__ void __launch_bounds__(256)
k_uid(const u64* __restrict__ tabk, u32 C, u32 Ucap, u32* __restrict__ tuid,
      u32* __restrict__ uidslot, u32* __restrict__ counter)
{
  u32 s=blockIdx.x*256+threadIdx.x;
  if(s>=C) return;
  if(tabk[s]==KEMPTY) return;
  u32 uid=atomicAdd(counter,1u);
  if(uid<Ucap) uidslot[uid]=s; else uid=0;
  tuid[s]=uid;
}

// ---------------- pass A: slot->uid translation + per-chunk LDS histogram ----------------
__global__ void __launch_bounds__(256)
k_hist(u32* __restrict__ inv, const u32* __restrict__ tuid,
       u32* __restrict__ hist, size_t M)
{
  __shared__ u32 h[BINS];
  u32 t=threadIdx.x, b=blockIdx.x;
#pragma unroll
  for(int j=0;j<(int)(BINS/256);j++) h[t+j*256]=0;
  __syncthreads();
  size_t base=(size_t)b*CHUNK;
#pragma unroll
  for(int j=0;j<(int)(CHUNK/256);j++){
    size_t i=base + (size_t)j*256 + t;
    if(i<M){
      u32 u=tuid[inv[i]];
      inv[i]=u;
      lds_addu(&h[u&(BINS-1)],1u);
    }
  }
  __syncthreads();
#pragma unroll
  for(int j=0;j<(int)(BINS/256);j++){
    u32 bin=t+j*256;
    hist[(size_t)b*BINS+bin]=h[bin];
  }
}

// ---------------- transpose: in[R][C] -> out[C][R] ----------------
__global__ void __launch_bounds__(256)
k_transpose(const u32* __restrict__ in, u32* __restrict__ out, u32 R, u32 C)
{
  __shared__ u32 tile[32][33];
  u32 bx=blockIdx.x, by=blockIdx.y;
  u32 tx=threadIdx.x&31, ty=threadIdx.x>>5;   // 32 x 8
  u32 c0=bx*32, r0=by*32;
#pragma unroll
  for(u32 j=0;j<32;j+=8){
    u32 r=r0+ty+j, c=c0+tx;
    if(r<R && c<C) tile[ty+j][tx]=in[(size_t)r*C+c];
  }
  __syncthreads();
#pragma unroll
  for(u32 j=0;j<32;j+=8){
    u32 c=c0+ty+j, r=r0+tx;
    if(c<C && r<R) out[(size_t)c*R+r]=tile[tx][ty+j];
  }
}

// ---------------- 3-level exclusive scan over histT (K items, mult of 1024) ----------------
__global__ void __launch_bounds__(256)
k_scan1(const u32* __restrict__ v, u32* __restrict__ bsum)
{
  __shared__ u32 sm[256];
  u32 t=threadIdx.x, b=blockIdx.x;
  size_t base=((size_t)b*256+t)*4;
  u32 s=v[base]+v[base+1]+v[base+2]+v[base+3];
  sm[t]=s; __syncthreads();
  for(int o=128;o>0;o>>=1){ if(t<(u32)o) sm[t]+=sm[t+o]; __syncthreads(); }
  if(t==0) bsum[b]=sm[0];
}

__global__ void __launch_bounds__(256)
k_scan2(u32* __restrict__ bsum, u32 nb)
{
  __shared__ u32 sm[256];
  u32 t=threadIdx.x;
  u32 per=(nb+255)/256;
  u32 lo=t*per, hi=lo+per; if(hi>nb) hi=nb; if(lo>nb) lo=nb;
  u32 tot=0;
  for(u32 i=lo;i<hi;i++) tot+=bsum[i];
  sm[t]=tot; __syncthreads();
  for(int o=1;o<256;o<<=1){
    u32 v=sm[t]; u32 a=(t>=(u32)o)?sm[t-o]:0u; __syncthreads();
    sm[t]=v+a; __syncthreads();
  }
  u32 run=sm[t]-tot;
  for(u32 i=lo;i<hi;i++){ u32 c=bsum[i]; bsum[i]=run; run+=c; }
}

__global__ void __launch_bounds__(256)
k_scan3(u32* __restrict__ v, const u32* __restrict__ bsum)
{
  __shared__ u32 sm[256];
  u32 t=threadIdx.x, b=blockIdx.x;
  size_t base=((size_t)b*256+t)*4;
  u32 c[4]; u32 tot=0;
#pragma unroll
  for(int j=0;j<4;j++){ c[j]=v[base+j]; tot+=c[j]; }
  sm[t]=tot; __syncthreads();
  for(int o=1;o<256;o<<=1){
    u32 x=sm[t]; u32 a=(t>=(u32)o)?sm[t-o]:0u; __syncthreads();
    sm[t]=x+a; __syncthreads();
  }
  u32 run=bsum[b]+sm[t]-tot;
#pragma unroll
  for(int j=0;j<4;j++){ v[base+j]=run; run+=c[j]; }
}

// ---------------- pass C: partition entries into bins (LDS cursors, no global atomics) ----------------
// skey packs (uid>>12)<<20 | point_index  (valid for N <= 2^20, Ucap <= 2^20)
__global__ void __launch_bounds__(256)
k_part(const u32* __restrict__ inv, const float* __restrict__ bary,
       const u32* __restrict__ histT, u32 nb,
       u32* __restrict__ skey, float* __restrict__ sw, size_t M)
{
  __shared__ u32 cur[BINS];
  u32 t=threadIdx.x, b=blockIdx.x;
#pragma unroll
  for(int j=0;j<(int)(BINS/256);j++){
    u32 bin=t+j*256;
    cur[bin]=histT[(size_t)bin*nb+b];
  }
  __syncthreads();
  size_t base=(size_t)b*CHUNK;
#pragma unroll
  for(int j=0;j<(int)(CHUNK/256);j++){
    size_t i=base+(size_t)j*256+t;
    if(i<M){
      u32 u=inv[i];
      u32 pos=lds_addu_rtn(&cur[u&(BINS-1)],1u);
      skey[pos]=((u>>12)<<20)|((u32)(i/6u));
      sw[pos]=bary[i];
    }
  }
}

// ---------------- queue build: split each bin into G=ceil(size/SPLIT) balanced slices ----------------
// q entry: bin[0:12) | g[12:22) | G[22:32)
__global__ void __launch_bounds__(256)
k_queue(const u32* __restrict__ histT, u32 nb, size_t M,
        u32* __restrict__ q, u32* __restrict__ qn)
{
  u32 b=blockIdx.x*256+threadIdx.x;
  if(b>=BINS) return;
  size_t s=histT[(size_t)b*nb];
  size_t e=(b+1<BINS)? (size_t)histT[(size_t)(b+1)*nb] : M;
  u32 sz=(u32)(e-s);
  if(sz==0) return;
  u32 G=(sz+SPLIT-1)/SPLIT; if(G>1023u) G=1023u;
  u32 base=atomicAdd(qn,G);
  for(u32 g=0; g<G; g++) q[base+g] = b | (g<<12) | (G<<22);
}

// ---------------- pass D: per-slice LDS accumulate + flush ----------------
// LDS row stride 17 floats: bank = (17*row + k) % 32 spreads uniformly for fixed k.
__global__ void __launch_bounds__(256)
k_accum(const u32* __restrict__ q, const u32* __restrict__ qn,
        const u32* __restrict__ skey, const float* __restrict__ sw,
        const float* __restrict__ values, const u32* __restrict__ histT,
        u32 nb, u32 rows, size_t M, float* __restrict__ v0)
{
  __shared__ float acc[4352];           // rows(<=256) * 17 floats (17 KB)
  u32 j=blockIdx.x;
  if(j>=*qn) return;
  u32 ent=q[j];
  u32 b=ent&4095u, g=(ent>>12)&1023u, G=ent>>22;
  size_t s0=histT[(size_t)b*nb];
  size_t e0=(b+1<BINS)? (size_t)histT[(size_t)(b+1)*nb] : M;
  u32 sz=(u32)(e0-s0);
  u32 chunk=(sz+G-1)/G;
  size_t s=s0+(size_t)g*chunk;
  size_t e=s+chunk; if(e>e0) e=e0;

  u32 t=threadIdx.x;
  for(u32 x=t;x<rows*17;x+=256) acc[x]=0.f;
  __syncthreads();

  if(G==1){
    // lane-per-entry, 4 entries/thread/iter, explicit register staging:
    // all 16 dwordx4 loads issued before any LDS atomic; relaxed atomics keep
    // the compiler from fencing loads behind ds_add.
    size_t base=s;
    for(; base+1024<=e; base+=1024){
      u32 key[4]; float w[4];
#pragma unroll
      for(int u4=0;u4<4;u4++){
        size_t i=base+(size_t)u4*256+t;
        key[u4]=skey[i]; w[u4]=sw[i];
      }
      float4 R[4][4];
#pragma unroll
      for(int u4=0;u4<4;u4++){
        const float4* vp=(const float4*)(values+(size_t)(key[u4]&0xFFFFFu)*16);
        R[u4][0]=vp[0]; R[u4][1]=vp[1]; R[u4][2]=vp[2]; R[u4][3]=vp[3];
      }
#pragma unroll
      for(int u4=0;u4<4;u4++){
        u32 a=(key[u4]>>20)*17;
        float ww=w[u4];
#pragma unroll
        for(int i4=0;i4<4;i4++){
          lds_add(&acc[a+4*i4+0], ww*R[u4][i4].x);
          lds_add(&acc[a+4*i4+1], ww*R[u4][i4].y);
          lds_add(&acc[a+4*i4+2], ww*R[u4][i4].z);
          lds_add(&acc[a+4*i4+3], ww*R[u4][i4].w);
        }
      }
    }
    for(; base<e; base+=256){
      size_t ei=base+t;
      if(ei<e){
        u32 key=skey[ei]; float w=sw[ei];
        const float4* vp=(const float4*)(values+(size_t)(key&0xFFFFFu)*16);
        float4 r0=vp[0],r1=vp[1],r2=vp[2],r3=vp[3];
        u32 a=(key>>20)*17;
        lds_add(&acc[a+ 0],w*r0.x); lds_add(&acc[a+ 1],w*r0.y); lds_add(&acc[a+ 2],w*r0.z); lds_add(&acc[a+ 3],w*r0.w);
        lds_add(&acc[a+ 4],w*r1.x); lds_add(&acc[a+ 5],w*r1.y); lds_add(&acc[a+ 6],w*r1.z); lds_add(&acc[a+ 7],w*r1.w);
        lds_add(&acc[a+ 8],w*r2.x); lds_add(&acc[a+ 9],w*r2.y); lds_add(&acc[a+10],w*r2.z); lds_add(&acc[a+11],w*r2.w);
        lds_add(&acc[a+12],w*r3.x); lds_add(&acc[a+13],w*r3.y); lds_add(&acc[a+14],w*r3.z); lds_add(&acc[a+15],w*r3.w);
      }
    }
  } else {
    // cooperative 16-lane path for hot (split) bins: same-uid entries dominate,
    // lane-per-entry would be a 64-way same-address LDS pileup; this is 4-way.
    u32 gr=t>>4, k=t&15;
    size_t base=s;
    for(; base+128<=e; base+=128){
      u32 key[8]; float w[8]; float x[8];
#pragma unroll
      for(int u8=0;u8<8;u8++){ size_t ei=base+(size_t)u8*16+gr; key[u8]=skey[ei]; w[u8]=sw[ei]; }
#pragma unroll
      for(int u8=0;u8<8;u8++){ x[u8]=values[(size_t)(key[u8]&0xFFFFFu)*16+k]; }
#pragma unroll
      for(int u8=0;u8<8;u8++) lds_add(&acc[(key[u8]>>20)*17+k], w[u8]*x[u8]);
    }
    for(; base<e; base+=16){
      size_t ei=base+gr;
      if(ei<e){
        u32 key=skey[ei]; float w=sw[ei];
        float x=values[(size_t)(key&0xFFFFFu)*16+k];
        lds_add(&acc[(key>>20)*17+k], w*x);
      }
    }
  }
  __syncthreads();

  if(G==1){
    for(u32 x=t;x<rows*16;x+=256){
      u32 row=x>>4, kk=x&15;
      v0[(size_t)((row<<12)|b)*16+kk]=acc[row*17+kk];
    }
  } else {
    for(u32 x=t;x<rows*16;x+=256){
      u32 row=x>>4, kk=x&15;
      float a=acc[row*17+kk];
      if(a!=0.f) atomAddF(&v0[(size_t)((row<<12)|b)*16+kk], a);
    }
  }
}

// ---------------- blur ----------------
__global__ void __launch_bounds__(256)
k_blur(const u64* __restrict__ tabk, const u32* __restrict__ tuid, u32 cmask,
       const u32* __restrict__ uidslot, const u32* __restrict__ counter, u32 Ucap,
       long long delta, const float* __restrict__ vin, float* __restrict__ vout)
{
  u32 m=blockIdx.x*256+threadIdx.x;
  u32 U=*counter; if(U>Ucap) U=Ucap;
  if(m>=U) return;
  long long code=(long long)tabk[uidslot[m]];
  long long sp=lookup_slot(tabk,cmask,(u64)(code+delta));
  long long sm=lookup_slot(tabk,cmask,(u64)(code-delta));
  float acc[16];
  row_load(vin+(size_t)m*16, acc);
#pragma unroll
  for(int k=0;k<16;k++) acc[k]*=0.5f;
  if(sp>=0){
    u32 u=tuid[sp]; float t[16]; row_load(vin+(size_t)u*16,t);
#pragma unroll
    for(int k=0;k<16;k++) acc[k]+=0.25f*t[k];
  }
  if(sm>=0){
    u32 u=tuid[sm]; float t[16]; row_load(vin+(size_t)u*16,t);
#pragma unroll
    for(int k=0;k<16;k++) acc[k]+=0.25f*t[k];
  }
  row_store(vout+(size_t)m*16, acc);
}

// ---------------- slice: 6 independent row gathers in flight ----------------
__global__ void __launch_bounds__(256)
k_slice(const u32* __restrict__ inv, const float* __restrict__ bary,
        const float* __restrict__ val, int N, float* __restrict__ out)
{
  int n=blockIdx.x*256+threadIdx.x;
  if(n>=N) return;
  u32 u[6]; float w[6];
#pragma unroll
  for(int r=0;r<6;r++){ u[r]=inv[(size_t)n*6+r]; w[r]=bary[(size_t)n*6+r]; }
  float t6[6][16];
#pragma unroll
  for(int r=0;r<6;r++) row_load(val+(size_t)u[r]*16, t6[r]);
  float acc[16];
#pragma unroll
  for(int k=0;k<16;k++){
    float a=w[0]*t6[0][k];
#pragma unroll
    for(int r=1;r<6;r++) a+=w[r]*t6[r][k];
    acc[k]=a;
  }
  const float alpha=0.9696969696969697f;
  float4* q=(float4*)(out+(size_t)n*16);
#pragma unroll
  for(int i=0;i<4;i++) q[i]=make_float4(alpha*acc[4*i],alpha*acc[4*i+1],alpha*acc[4*i+2],alpha*acc[4*i+3]);
}

__global__ void k_diag(float* out, float v){ out[0]=v; }

// ---------------- host ----------------
extern "C" void kernel_launch(void* const* d_in, const int* in_sizes, int n_in,
                              void* d_out, int out_size, void* d_ws, size_t ws_size,
                              hipStream_t stream)
{
  const float* feat   =(const float*)d_in[0];
  const float* values =(const float*)d_in[1];
  float* out=(float*)d_out;
  int N=in_sizes[0]/5;
  size_t M=(size_t)N*6;

  u32 nb=(u32)((M+CHUNK-1)/CHUNK);          // #chunks in hist/part passes
  size_t K=(size_t)nb*BINS;                  // histogram matrix size
  const u32 QCAP=16384;

  // v1 doubles as scratch: hist[K] histT[K] skey[M] sw[M] bsum[K/1024] q[QCAP] qn
  auto v1bytes=[&](size_t U)->size_t{
    size_t a=U*64;
    size_t b=K*4+K*4+M*4+M*4+(K/1024)*4+QCAP*4+1024;
    return a>b?a:b;
  };
  auto need=[&](int lC,int lU)->size_t{
    size_t C=1ull<<lC, U=1ull<<lU, s=0;
    auto al=[&](size_t b){ s=(s+255)&~(size_t)255; s+=b; };
    al(4); al(M*4); al(M*4); al(C*8); al(C*4); al(U*4); al(U*64); al(v1bytes(U));
    return s+256;
  };
  const int prefs[4][2]={{22,20},{21,20},{21,19},{20,18}};
  int lC=0,lU=0;
  for(int i=0;i<4;i++){ if(need(prefs[i][0],prefs[i][1])<=ws_size){ lC=prefs[i][0]; lU=prefs[i][1]; break; } }
  if(!lC){
    hipMemsetAsync(d_out,0,(size_t)out_size*sizeof(float),stream);
    k_diag<<<1,1,0,stream>>>(out,(float)(ws_size>>20));
    return;
  }

  size_t C=1ull<<lC, Ucap=1ull<<lU; u32 cmask=(u32)(C-1);
  char* base=(char*)d_ws; size_t offb=0;
  auto carve=[&](size_t b)->char*{ offb=(offb+255)&~(size_t)255; char* p=base+offb; offb+=b; return p; };
  u32*   counter=(u32*)carve(4);
  u32*   inv    =(u32*)carve(M*4);
  float* bary   =(float*)carve(M*4);
  u64*   tabk   =(u64*)carve(C*8);
  u32*   tuid   =(u32*)carve(C*4);
  u32*   uidslot=(u32*)carve(Ucap*4);
  float* v0     =(float*)carve(Ucap*64);
  float* v1     =(float*)carve(v1bytes(Ucap));

  u32*   hist =(u32*)v1;
  u32*   histT=hist+K;
  u32*   skey =histT+K;
  float* sw   =(float*)(skey+M);
  u32*   bsum =(u32*)(sw+M);
  u32*   q    =bsum+(K/1024);
  u32*   qn   =q+QCAP;

  hipMemsetAsync(counter,0,4,stream);
  hipMemsetAsync(qn,0,4,stream);
  hipMemsetAsync(tabk,0xFF,C*8,stream);
  hipMemsetAsync(v0,0,Ucap*64,stream);   // zero-init for split-bin atomic flush

  const int B=256;
  k_setup<<<(N+B-1)/B,B,0,stream>>>(feat,N,tabk,cmask,inv,bary);
  k_uid  <<<(u32)((C+B-1)/B),B,0,stream>>>(tabk,(u32)C,(u32)Ucap,tuid,uidslot,counter);

  k_hist <<<nb,B,0,stream>>>(inv,tuid,hist,M);
  {
    dim3 g((BINS+31)/32,(nb+31)/32);
    k_transpose<<<g,B,0,stream>>>(hist,histT,nb,BINS);   // hist[nb][BINS] -> histT[BINS][nb]
  }
  u32 sb=(u32)(K/1024);                                  // K is a multiple of 1024
  k_scan1<<<sb,B,0,stream>>>(histT,bsum);
  k_scan2<<<1 ,B,0,stream>>>(bsum,sb);
  k_scan3<<<sb,B,0,stream>>>(histT,bsum);
  k_part <<<nb,B,0,stream>>>(inv,bary,histT,nb,skey,sw,M);

  k_queue<<<(BINS+B-1)/B,B,0,stream>>>(histT,nb,M,q,qn);

  u32 rows=(u32)(Ucap>>12);
  k_accum<<<QCAP,B,0,stream>>>(q,qn,skey,sw,values,histT,nb,rows,M,v0);

  const long long P[5]={1ll,2048ll,1ll<<22,1ll<<33,1ll<<44};
  const long long SUM=P[0]+P[1]+P[2]+P[3]+P[4];
  u32 gb=(u32)((Ucap+B-1)/B);
  float* a=v0; float* bb=v1;
  for(int j=0;j<6;j++){
    long long delta=(j<5)? (SUM-6*P[4-j]) : SUM;
    k_blur<<<gb,B,0,stream>>>(tabk,tuid,cmask,uidslot,counter,(u32)Ucap,delta,a,bb);
    float* t=a; a=bb; bb=t;
  }
  k_slice<<<(N+B-1)/B,B,0,stream>>>(inv,bary,a,N,out);
}

// Round 10
// 1219.025 us; speedup vs baseline: 2.2400x; 1.1662x over previous
//
#include <hip/hip_runtime.h>
#include <stdint.h>

typedef unsigned long long u64;
typedef unsigned int u32;

static constexpr u64 KEMPTY = ~0ull;
static constexpr int PROBE_CAP = 32768;
static constexpr u32 BINS  = 4096;   // partition on uid & 4095 (hash-uniform)
static constexpr u32 CHUNK = 4096;   // entries per block in hist/part passes
static constexpr u32 SPLIT = 2048;   // max entries per accum work-item (tail control)

// ---- stream-splat path (active when U <= THRESH) ----
static constexpr u32 RPP    = 960;            // uid rows per LDS tile (960*17*4 = 65280 B < 64 KiB)
static constexpr u32 TOTAL_B= 512;            // saccum blocks (2/CU * 256 CU)
static constexpr u32 PMAX   = 24;             // max passes
static constexpr u32 THRESH = RPP*PMAX;       // 23040 unique vertices

static __device__ __forceinline__ u64 mix64(u64 x){
  x ^= x >> 30; x *= 0xbf58476d1ce4e5b9ull;
  x ^= x >> 27; x *= 0x94d049bb133111ebull;
  x ^= x >> 31; return x;
}

static __device__ __forceinline__ long long lookup_slot(const u64* __restrict__ tk, u32 cmask, u64 code){
  u32 h = (u32)mix64(code) & cmask;
#pragma unroll 1
  for(int p=0;p<PROBE_CAP;p++){
    u64 cur = tk[h];
    if(cur==code) return (long long)h;
    if(cur==KEMPTY) return -1;
    h=(h+1)&cmask;
  }
  return -1;
}

static __device__ __forceinline__ void atomAddF(float* p, float v){
#if defined(__gfx90a__) || defined(__gfx940__) || defined(__gfx941__) || defined(__gfx942__) || defined(__gfx950__)
  unsafeAtomicAdd(p, v);
#else
  atomicAdd(p, v);
#endif
}

static __device__ __forceinline__ void lds_add(float* p, float v){
  __hip_atomic_fetch_add(p, v, __ATOMIC_RELAXED, __HIP_MEMORY_SCOPE_WORKGROUP);
}
static __device__ __forceinline__ void lds_addu(u32* p, u32 v){
  __hip_atomic_fetch_add(p, v, __ATOMIC_RELAXED, __HIP_MEMORY_SCOPE_WORKGROUP);
}
static __device__ __forceinline__ u32 lds_addu_rtn(u32* p, u32 v){
  return __hip_atomic_fetch_add(p, v, __ATOMIC_RELAXED, __HIP_MEMORY_SCOPE_WORKGROUP);
}

static __device__ __forceinline__ void row_load(const float* __restrict__ p, float* o){
  const float4* q=(const float4*)p;
#pragma unroll
  for(int i=0;i<4;i++){ float4 v=q[i]; o[4*i]=v.x; o[4*i+1]=v.y; o[4*i+2]=v.z; o[4*i+3]=v.w; }
}
static __device__ __forceinline__ void row_store(float* __restrict__ p, const float* o){
  float4* q=(float4*)p;
#pragma unroll
  for(int i=0;i<4;i++) q[i]=make_float4(o[4*i],o[4*i+1],o[4*i+2],o[4*i+3]);
}

// ---------------- kernel 1: elevate/rank/bary + table insert; stores SLOT in inv ----------------
__global__ void __launch_bounds__(256)
k_setup(const float* __restrict__ feat, int N,
        u64* __restrict__ tabk, u32 cmask,
        u32* __restrict__ inv_slot, float* __restrict__ bary)
{
#pragma clang fp contract(off)
  int n = blockIdx.x*256 + threadIdx.x;
  if(n>=N) return;

  const float s0=3.4641016151377544f, s1=2.0f, s2=1.4142135623730951f,
              s3=1.0954451150103321f, s4=0.8944271909999159f;
  float c[5];
  c[0]=feat[n*5+0]*s0; c[1]=feat[n*5+1]*s1; c[2]=feat[n*5+2]*s2;
  c[3]=feat[n*5+3]*s3; c[4]=feat[n*5+4]*s4;

  float sfx[6]; sfx[5]=0.f;
#pragma unroll
  for(int i=4;i>=0;i--) sfx[i]=sfx[i+1]+c[i];
  float el[6];
  el[0]=sfx[0];
#pragma unroll
  for(int i=1;i<6;i++) el[i]=sfx[i]-(float)i*c[i-1];

  const float down=1.0f/6.0f;
  float rd[6], rem0[6], rdsum=0.f;
#pragma unroll
  for(int i=0;i<6;i++){ rd[i]=rintf(el[i]*down); rem0[i]=rd[i]*6.0f; rdsum+=rd[i]; }
  int sumi=(int)rdsum;

  float diff[6];
#pragma unroll
  for(int i=0;i<6;i++) diff[i]=(el[i]-rem0[i])*down;

  int rank[6];
#pragma unroll
  for(int i=0;i<6;i++){
    int r=0;
#pragma unroll
    for(int j=0;j<6;j++)
      r += (diff[j]>diff[i]) || (diff[j]==diff[i] && j<i);
    rank[i]=r+sumi;
  }
  int rem0i[6];
#pragma unroll
  for(int i=0;i<6;i++){
    rem0i[i]=(int)rem0[i];
    int sh=(rank[i]<0)-(rank[i]>5);
    rank[i]+=6*sh; rem0i[i]+=6*sh;
  }

  float b[7]={0.f,0.f,0.f,0.f,0.f,0.f,0.f};
#pragma unroll
  for(int i=0;i<6;i++){
    float t=(el[i]-(float)rem0i[i])*down;
    int k0=5-rank[i]; if(k0>=0&&k0<7) b[k0]+=t;
  }
#pragma unroll
  for(int i=0;i<6;i++){
    float t=(el[i]-(float)rem0i[i])*down;
    int k1=6-rank[i]; if(k1>=0&&k1<7) b[k1]-=t;
  }
  bary[(size_t)n*6+0]=(b[0]+1.0f)+b[6];
#pragma unroll
  for(int r=1;r<6;r++) bary[(size_t)n*6+r]=b[r];

#pragma unroll 1
  for(int r=0;r<6;r++){
    long long code=0;
#pragma unroll
    for(int i=0;i<5;i++){
      int key = rem0i[i] + ((rank[i] >= 6-r) ? (r-6) : r);
      code = code*2048 + (long long)(key+1024);
    }
    u32 h=(u32)mix64((u64)code)&cmask;
    u32 slot=0xFFFFFFFFu;
#pragma unroll 1
    for(int p=0;p<PROBE_CAP;p++){
      u64 cur=tabk[h];
      if(cur==(u64)code){ slot=h; break; }
      if(cur==KEMPTY){
        u64 old=atomicCAS((unsigned long long*)&tabk[h], KEMPTY, (u64)code);
        if(old==KEMPTY || old==(u64)code){ slot=h; break; }
      } else {
        h=(h+1)&cmask;
      }
    }
    inv_slot[(size_t)n*6+r]=slot;
  }
}

// ---------------- kernel 2: compact uids ----------------
__global__ void __launch_bounds__(256)
k_uid(const u64* __restrict__ tabk, u32 C, u32 Ucap, u32* __restrict__ tuid,
      u32* __restrict__ uidslot, u32* __restrict__ counter)
{
  u32 s=blockIdx.x*256+threadIdx.x;
  if(s>=C) return;
  if(tabk[s]==KEMPTY) return;
  u32 uid=atomicAdd(counter,1u);
  if(uid<Ucap) uidslot[uid]=s; else uid=0;
  tuid[s]=uid;
}

// ---------------- kernel 3: slot -> uid translation (always runs) ----------------
__global__ void __launch_bounds__(256)
k_translate(u32* __restrict__ inv, const u32* __restrict__ tuid, size_t M)
{
  size_t i=(size_t)blockIdx.x*256+threadIdx.x;
  if(i<M) inv[i]=tuid[inv[i]];
}

// ================= STREAM-SPLAT PATH (U <= THRESH) =================
// one block = (pass, sub): scans its point range coalescedly, accumulates the
// uid rows of its pass window in a 960-row LDS tile, flushes a partial tile.
__global__ void __launch_bounds__(256)
k_saccum(const u32* __restrict__ inv, const float* __restrict__ bary,
         const float* __restrict__ values, const u32* __restrict__ counter,
         u32 Ucap, int N, float* __restrict__ partial)
{
  __shared__ float acc[RPP*17];
  u32 U=*counter; if(U>Ucap) U=Ucap;
  if(U>THRESH) return;
  u32 P=(U+RPP-1)/RPP;
  u32 S=TOTAL_B/P;
  u32 j=blockIdx.x;
  if(j>=P*S) return;
  u32 pass=j/S, sub=j-pass*S;
  u32 lo=pass*RPP;
  u32 t=threadIdx.x;
  for(u32 x=t;x<RPP*17;x+=256) acc[x]=0.f;
  __syncthreads();

  size_t p0=((size_t)sub*(size_t)N)/S;
  size_t p1=((size_t)(sub+1)*(size_t)N)/S;
  for(size_t i=p0+t;i<p1;i+=256){
    const u32* ip=inv+i*6;
    const float* bp=bary+i*6;
    u32 u[6]; float w[6];
#pragma unroll
    for(int r=0;r<6;r++){ u[r]=ip[r]-lo; w[r]=bp[r]; }
    bool any=false;
#pragma unroll
    for(int r=0;r<6;r++) any = any | (u[r]<RPP);
    if(!any) continue;
    float v[16];
    row_load(values+(size_t)i*16, v);
#pragma unroll
    for(int r=0;r<6;r++){
      if(u[r]<RPP){
        u32 a=u[r]*17; float ww=w[r];
#pragma unroll
        for(int k=0;k<16;k++) lds_add(&acc[a+k], ww*v[k]);
      }
    }
  }
  __syncthreads();
  float* dst=partial+(size_t)j*(RPP*17);
  for(u32 x=t;x<RPP*17;x+=256) dst[x]=acc[x];
}

// sum the S partial tiles of each pass into v0
__global__ void __launch_bounds__(256)
k_reduce(const float* __restrict__ partial, const u32* __restrict__ counter,
         u32 Ucap, float* __restrict__ v0)
{
  u32 U=*counter; if(U>Ucap) U=Ucap;
  if(U>THRESH) return;
  u32 P=(U+RPP-1)/RPP, S=TOTAL_B/P;
  const u32 RG=RPP/16;                    // 60 row-groups per pass
  u32 bid=blockIdx.x;
  u32 pass=bid/RG, rg=bid-pass*RG;
  if(pass>=P) return;
  u32 t=threadIdx.x;
  u32 r16=t>>4, k=t&15;
  u32 lrow=rg*16+r16;
  u32 gu=pass*RPP+lrow;
  const float* base=partial+((size_t)pass*S)*(RPP*17)+(size_t)lrow*17+k;
  float s=0.f;
  for(u32 ss=0;ss<S;ss++) s+=base[(size_t)ss*(RPP*17)];
  if(gu<U) v0[(size_t)gu*16+k]=s;
}

// ================= PARTITION PATH (U > THRESH) =================
__global__ void __launch_bounds__(256)
k_hist(const u32* __restrict__ inv, const u32* __restrict__ counter,
       u32* __restrict__ hist, size_t M)
{
  if(*counter<=THRESH) return;
  __shared__ u32 h[BINS];
  u32 t=threadIdx.x, b=blockIdx.x;
#pragma unroll
  for(int j=0;j<(int)(BINS/256);j++) h[t+j*256]=0;
  __syncthreads();
  size_t base=(size_t)b*CHUNK;
#pragma unroll
  for(int j=0;j<(int)(CHUNK/256);j++){
    size_t i=base + (size_t)j*256 + t;
    if(i<M){
      u32 u=inv[i];
      lds_addu(&h[u&(BINS-1)],1u);
    }
  }
  __syncthreads();
#pragma unroll
  for(int j=0;j<(int)(BINS/256);j++){
    u32 bin=t+j*256;
    hist[(size_t)b*BINS+bin]=h[bin];
  }
}

__global__ void __launch_bounds__(256)
k_transpose(const u32* __restrict__ in, u32* __restrict__ out, u32 R, u32 C,
            const u32* __restrict__ counter)
{
  if(*counter<=THRESH) return;
  __shared__ u32 tile[32][33];
  u32 bx=blockIdx.x, by=blockIdx.y;
  u32 tx=threadIdx.x&31, ty=threadIdx.x>>5;
  u32 c0=bx*32, r0=by*32;
#pragma unroll
  for(u32 j=0;j<32;j+=8){
    u32 r=r0+ty+j, c=c0+tx;
    if(r<R && c<C) tile[ty+j][tx]=in[(size_t)r*C+c];
  }
  __syncthreads();
#pragma unroll
  for(u32 j=0;j<32;j+=8){
    u32 c=c0+ty+j, r=r0+tx;
    if(c<C && r<R) out[(size_t)c*R+r]=tile[tx][ty+j];
  }
}

__global__ void __launch_bounds__(256)
k_scan1(const u32* __restrict__ v, u32* __restrict__ bsum, const u32* __restrict__ counter)
{
  if(*counter<=THRESH) return;
  __shared__ u32 sm[256];
  u32 t=threadIdx.x, b=blockIdx.x;
  size_t base=((size_t)b*256+t)*4;
  u32 s=v[base]+v[base+1]+v[base+2]+v[base+3];
  sm[t]=s; __syncthreads();
  for(int o=128;o>0;o>>=1){ if(t<(u32)o) sm[t]+=sm[t+o]; __syncthreads(); }
  if(t==0) bsum[b]=sm[0];
}

__global__ void __launch_bounds__(256)
k_scan2(u32* __restrict__ bsum, u32 nb, const u32* __restrict__ counter)
{
  if(*counter<=THRESH) return;
  __shared__ u32 sm[256];
  u32 t=threadIdx.x;
  u32 per=(nb+255)/256;
  u32 lo=t*per, hi=lo+per; if(hi>nb) hi=nb; if(lo>nb) lo=nb;
  u32 tot=0;
  for(u32 i=lo;i<hi;i++) tot+=bsum[i];
  sm[t]=tot; __syncthreads();
  for(int o=1;o<256;o<<=1){
    u32 v=sm[t]; u32 a=(t>=(u32)o)?sm[t-o]:0u; __syncthreads();
    sm[t]=v+a; __syncthreads();
  }
  u32 run=sm[t]-tot;
  for(u32 i=lo;i<hi;i++){ u32 c=bsum[i]; bsum[i]=run; run+=c; }
}

__global__ void __launch_bounds__(256)
k_scan3(u32* __restrict__ v, const u32* __restrict__ bsum, const u32* __restrict__ counter)
{
  if(*counter<=THRESH) return;
  __shared__ u32 sm[256];
  u32 t=threadIdx.x, b=blockIdx.x;
  size_t base=((size_t)b*256+t)*4;
  u32 c[4]; u32 tot=0;
#pragma unroll
  for(int j=0;j<4;j++){ c[j]=v[base+j]; tot+=c[j]; }
  sm[t]=tot; __syncthreads();
  for(int o=1;o<256;o<<=1){
    u32 x=sm[t]; u32 a=(t>=(u32)o)?sm[t-o]:0u; __syncthreads();
    sm[t]=x+a; __syncthreads();
  }
  u32 run=bsum[b]+sm[t]-tot;
#pragma unroll
  for(int j=0;j<4;j++){ v[base+j]=run; run+=c[j]; }
}

__global__ void __launch_bounds__(256)
k_part(const u32* __restrict__ inv, const float* __restrict__ bary,
       const u32* __restrict__ histT, u32 nb,
       u32* __restrict__ skey, float* __restrict__ sw, size_t M,
       const u32* __restrict__ counter)
{
  if(*counter<=THRESH) return;
  __shared__ u32 cur[BINS];
  u32 t=threadIdx.x, b=blockIdx.x;
#pragma unroll
  for(int j=0;j<(int)(BINS/256);j++){
    u32 bin=t+j*256;
    cur[bin]=histT[(size_t)bin*nb+b];
  }
  __syncthreads();
  size_t base=(size_t)b*CHUNK;
#pragma unroll
  for(int j=0;j<(int)(CHUNK/256);j++){
    size_t i=base+(size_t)j*256+t;
    if(i<M){
      u32 u=inv[i];
      u32 pos=lds_addu_rtn(&cur[u&(BINS-1)],1u);
      skey[pos]=((u>>12)<<20)|((u32)(i/6u));
      sw[pos]=bary[i];
    }
  }
}

__global__ void __launch_bounds__(256)
k_queue(const u32* __restrict__ histT, u32 nb, size_t M,
        u32* __restrict__ q, u32* __restrict__ qn, const u32* __restrict__ counter)
{
  if(*counter<=THRESH) return;
  u32 b=blockIdx.x*256+threadIdx.x;
  if(b>=BINS) return;
  size_t s=histT[(size_t)b*nb];
  size_t e=(b+1<BINS)? (size_t)histT[(size_t)(b+1)*nb] : M;
  u32 sz=(u32)(e-s);
  if(sz==0) return;
  u32 G=(sz+SPLIT-1)/SPLIT; if(G>1023u) G=1023u;
  u32 base=atomicAdd(qn,G);
  for(u32 g=0; g<G; g++) q[base+g] = b | (g<<12) | (G<<22);
}

__global__ void __launch_bounds__(256)
k_accum(const u32* __restrict__ q, const u32* __restrict__ qn,
        const u32* __restrict__ skey, const float* __restrict__ sw,
        const float* __restrict__ values, const u32* __restrict__ histT,
        u32 nb, u32 rows, size_t M, float* __restrict__ v0)
{
  __shared__ float acc[4352];
  u32 j=blockIdx.x;
  if(j>=*qn) return;
  u32 ent=q[j];
  u32 b=ent&4095u, g=(ent>>12)&1023u, G=ent>>22;
  size_t s0=histT[(size_t)b*nb];
  size_t e0=(b+1<BINS)? (size_t)histT[(size_t)(b+1)*nb] : M;
  u32 sz=(u32)(e0-s0);
  u32 chunk=(sz+G-1)/G;
  size_t s=s0+(size_t)g*chunk;
  size_t e=s+chunk; if(e>e0) e=e0;

  u32 t=threadIdx.x;
  for(u32 x=t;x<rows*17;x+=256) acc[x]=0.f;
  __syncthreads();

  if(G==1){
    size_t base=s;
    for(; base+512<=e; base+=512){
      size_t i0=base+t, i1=base+256+t;
      u32 key0=skey[i0], key1=skey[i1];
      float w0=sw[i0], w1=sw[i1];
      float r0[16], r1[16];
      row_load(values+(size_t)(key0&0xFFFFFu)*16, r0);
      row_load(values+(size_t)(key1&0xFFFFFu)*16, r1);
      u32 a0=(key0>>20)*17, a1=(key1>>20)*17;
#pragma unroll
      for(int k=0;k<16;k++) lds_add(&acc[a0+k], w0*r0[k]);
#pragma unroll
      for(int k=0;k<16;k++) lds_add(&acc[a1+k], w1*r1[k]);
    }
    for(; base<e; base+=256){
      size_t ei=base+t;
      if(ei<e){
        u32 key=skey[ei]; float w=sw[ei];
        float r[16];
        row_load(values+(size_t)(key&0xFFFFFu)*16, r);
        u32 a=(key>>20)*17;
#pragma unroll
        for(int k=0;k<16;k++) lds_add(&acc[a+k], w*r[k]);
      }
    }
  } else {
    u32 gr=t>>4, k=t&15;
    size_t base=s;
    for(; base+128<=e; base+=128){
      u32 key[8]; float w[8]; float x[8];
#pragma unroll
      for(int u8=0;u8<8;u8++){ size_t ei=base+(size_t)u8*16+gr; key[u8]=skey[ei]; w[u8]=sw[ei]; }
#pragma unroll
      for(int u8=0;u8<8;u8++){ x[u8]=values[(size_t)(key[u8]&0xFFFFFu)*16+k]; }
#pragma unroll
      for(int u8=0;u8<8;u8++) lds_add(&acc[(key[u8]>>20)*17+k], w[u8]*x[u8]);
    }
    for(; base<e; base+=16){
      size_t ei=base+gr;
      if(ei<e){
        u32 key=skey[ei]; float w=sw[ei];
        float x=values[(size_t)(key&0xFFFFFu)*16+k];
        lds_add(&acc[(key>>20)*17+k], w*x);
      }
    }
  }
  __syncthreads();

  if(G==1){
    for(u32 x=t;x<rows*16;x+=256){
      u32 row=x>>4, kk=x&15;
      v0[(size_t)((row<<12)|b)*16+kk]=acc[row*17+kk];
    }
  } else {
    for(u32 x=t;x<rows*16;x+=256){
      u32 row=x>>4, kk=x&15;
      float a=acc[row*17+kk];
      if(a!=0.f) atomAddF(&v0[(size_t)((row<<12)|b)*16+kk], a);
    }
  }
}

// ---------------- blur ----------------
__global__ void __launch_bounds__(256)
k_blur(const u64* __restrict__ tabk, const u32* __restrict__ tuid, u32 cmask,
       const u32* __restrict__ uidslot, const u32* __restrict__ counter, u32 Ucap,
       long long delta, const float* __restrict__ vin, float* __restrict__ vout)
{
  u32 m=blockIdx.x*256+threadIdx.x;
  u32 U=*counter; if(U>Ucap) U=Ucap;
  if(m>=U) return;
  long long code=(long long)tabk[uidslot[m]];
  long long sp=lookup_slot(tabk,cmask,(u64)(code+delta));
  long long sm=lookup_slot(tabk,cmask,(u64)(code-delta));
  float acc[16];
  row_load(vin+(size_t)m*16, acc);
#pragma unroll
  for(int k=0;k<16;k++) acc[k]*=0.5f;
  if(sp>=0){
    u32 u=tuid[sp]; float t[16]; row_load(vin+(size_t)u*16,t);
#pragma unroll
    for(int k=0;k<16;k++) acc[k]+=0.25f*t[k];
  }
  if(sm>=0){
    u32 u=tuid[sm]; float t[16]; row_load(vin+(size_t)u*16,t);
#pragma unroll
    for(int k=0;k<16;k++) acc[k]+=0.25f*t[k];
  }
  row_store(vout+(size_t)m*16, acc);
}

// ---------------- slice ----------------
__global__ void __launch_bounds__(256)
k_slice(const u32* __restrict__ inv, const float* __restrict__ bary,
        const float* __restrict__ val, int N, float* __restrict__ out)
{
  int n=blockIdx.x*256+threadIdx.x;
  if(n>=N) return;
  u32 u[6]; float w[6];
#pragma unroll
  for(int r=0;r<6;r++){ u[r]=inv[(size_t)n*6+r]; w[r]=bary[(size_t)n*6+r]; }
  float t6[6][16];
#pragma unroll
  for(int r=0;r<6;r++) row_load(val+(size_t)u[r]*16, t6[r]);
  float acc[16];
#pragma unroll
  for(int k=0;k<16;k++){
    float a=w[0]*t6[0][k];
#pragma unroll
    for(int r=1;r<6;r++) a+=w[r]*t6[r][k];
    acc[k]=a;
  }
  const float alpha=0.9696969696969697f;
  float4* q=(float4*)(out+(size_t)n*16);
#pragma unroll
  for(int i=0;i<4;i++) q[i]=make_float4(alpha*acc[4*i],alpha*acc[4*i+1],alpha*acc[4*i+2],alpha*acc[4*i+3]);
}

__global__ void k_diag(float* out, float v){ out[0]=v; }

// ---------------- host ----------------
extern "C" void kernel_launch(void* const* d_in, const int* in_sizes, int n_in,
                              void* d_out, int out_size, void* d_ws, size_t ws_size,
                              hipStream_t stream)
{
  const float* feat   =(const float*)d_in[0];
  const float* values =(const float*)d_in[1];
  float* out=(float*)d_out;
  int N=in_sizes[0]/5;
  size_t M=(size_t)N*6;

  u32 nb=(u32)((M+CHUNK-1)/CHUNK);
  size_t K=(size_t)nb*BINS;
  const u32 QCAP=16384;

  // v1 union: partition scratch {hist,histT,skey,sw,bsum,q,qn}  OR  stream partial tiles
  size_t partial_bytes=(size_t)TOTAL_B*(RPP*17)*4;   // 33.4 MB
  auto v1bytes=[&](size_t U)->size_t{
    size_t a=U*64;
    size_t b=K*4+K*4+M*4+M*4+(K/1024)*4+QCAP*4+1024;
    size_t c=partial_bytes;
    size_t m1=a>b?a:b;
    return m1>c?m1:c;
  };
  auto need=[&](int lC,int lU)->size_t{
    size_t C=1ull<<lC, U=1ull<<lU, s=0;
    auto al=[&](size_t b){ s=(s+255)&~(size_t)255; s+=b; };
    al(4); al(M*4); al(M*4); al(C*8); al(C*4); al(U*4); al(U*64); al(v1bytes(U));
    return s+256;
  };
  const int prefs[4][2]={{22,20},{21,20},{21,19},{20,18}};
  int lC=0,lU=0;
  for(int i=0;i<4;i++){ if(need(prefs[i][0],prefs[i][1])<=ws_size){ lC=prefs[i][0]; lU=prefs[i][1]; break; } }
  if(!lC){
    hipMemsetAsync(d_out,0,(size_t)out_size*sizeof(float),stream);
    k_diag<<<1,1,0,stream>>>(out,(float)(ws_size>>20));
    return;
  }

  size_t C=1ull<<lC, Ucap=1ull<<lU; u32 cmask=(u32)(C-1);
  char* base=(char*)d_ws; size_t offb=0;
  auto carve=[&](size_t b)->char*{ offb=(offb+255)&~(size_t)255; char* p=base+offb; offb+=b; return p; };
  u32*   counter=(u32*)carve(4);
  u32*   inv    =(u32*)carve(M*4);
  float* bary   =(float*)carve(M*4);
  u64*   tabk   =(u64*)carve(C*8);
  u32*   tuid   =(u32*)carve(C*4);
  u32*   uidslot=(u32*)carve(Ucap*4);
  float* v0     =(float*)carve(Ucap*64);
  float* v1     =(float*)carve(v1bytes(Ucap));

  // partition scratch aliases
  u32*   hist =(u32*)v1;
  u32*   histT=hist+K;
  u32*   skey =histT+K;
  float* sw   =(float*)(skey+M);
  u32*   bsum =(u32*)(sw+M);
  u32*   q    =bsum+(K/1024);
  u32*   qn   =q+QCAP;
  // stream scratch alias
  float* partial=(float*)v1;

  hipMemsetAsync(counter,0,4,stream);
  hipMemsetAsync(qn,0,4,stream);          // must precede k_queue; harmless aliasing w/ partial (queue path only reads it when U>THRESH, and then partial is never written)
  hipMemsetAsync(tabk,0xFF,C*8,stream);
  hipMemsetAsync(v0,0,Ucap*64,stream);

  const int B=256;
  k_setup    <<<(N+B-1)/B,B,0,stream>>>(feat,N,tabk,cmask,inv,bary);
  k_uid      <<<(u32)((C+B-1)/B),B,0,stream>>>(tabk,(u32)C,(u32)Ucap,tuid,uidslot,counter);
  k_translate<<<(u32)((M+B-1)/B),B,0,stream>>>(inv,tuid,M);

  // ---- stream path (dead if U>THRESH) ----
  k_saccum<<<TOTAL_B,B,0,stream>>>(inv,bary,values,counter,(u32)Ucap,N,partial);
  k_reduce<<<PMAX*(RPP/16),B,0,stream>>>(partial,counter,(u32)Ucap,v0);

  // ---- partition path (dead if U<=THRESH) ----
  // NOTE: qn aliases the partial region; re-zero it AFTER saccum/reduce so the
  // partition path still sees qn==0 -> but k_queue writes it anyway. To keep both
  // paths safe we re-memset qn here (stream mode: partial is already consumed).
  hipMemsetAsync(qn,0,4,stream);
  k_hist <<<nb,B,0,stream>>>(inv,counter,hist,M);
  {
    dim3 g((BINS+31)/32,(nb+31)/32);
    k_transpose<<<g,B,0,stream>>>(hist,histT,nb,BINS,counter);
  }
  u32 sb=(u32)(K/1024);
  k_scan1<<<sb,B,0,stream>>>(histT,bsum,counter);
  k_scan2<<<1 ,B,0,stream>>>(bsum,sb,counter);
  k_scan3<<<sb,B,0,stream>>>(histT,bsum,counter);
  k_part <<<nb,B,0,stream>>>(inv,bary,histT,nb,skey,sw,M,counter);
  k_queue<<<(BINS+B-1)/B,B,0,stream>>>(histT,nb,M,q,qn,counter);

  u32 rows=(u32)(Ucap>>12);
  k_accum<<<QCAP,B,0,stream>>>(q,qn,skey,sw,values,histT,nb,rows,M,v0);

  const long long P[5]={1ll,2048ll,1ll<<22,1ll<<33,1ll<<44};
  const long long SUM=P[0]+P[1]+P[2]+P[3]+P[4];
  u32 gb=(u32)((Ucap+B-1)/B);
  float* a=v0; float* bb=v1;
  for(int j=0;j<6;j++){
    long long delta=(j<5)? (SUM-6*P[4-j]) : SUM;
    k_blur<<<gb,B,0,stream>>>(tabk,tuid,cmask,uidslot,counter,(u32)Ucap,delta,a,bb);
    float* t=a; a=bb; bb=t;
  }
  k_slice<<<(N+B-1)/B,B,0,stream>>>(inv,bary,a,N,out);
}

// Round 11
// 1190.021 us; speedup vs baseline: 2.2946x; 1.0244x over previous
//
#include <hip/hip_runtime.h>
#include <stdint.h>

typedef unsigned long long u64;
typedef unsigned int u32;

static constexpr u64 KEMPTY = ~0ull;
static constexpr int PROBE_CAP = 32768;
static constexpr u32 BINS  = 4096;   // partition on uid & 4095 (hash-uniform)
static constexpr u32 CHUNK = 4096;   // entries per block in hist/part passes
static constexpr u32 SPLIT = 2048;   // max entries per accum work-item (tail control)

// ---- stream-splat path (active when U <= THRESH) ----
static constexpr u32 RPP    = 960;            // uid rows per LDS tile (960*17*4 = 65280 B < 64 KiB)
static constexpr u32 TOTAL_B= 512;            // saccum blocks (2/CU * 256 CU)
static constexpr u32 PMAX   = 24;             // max passes
static constexpr u32 THRESH = RPP*PMAX;       // 23040 unique vertices

static __device__ __forceinline__ u64 mix64(u64 x){
  x ^= x >> 30; x *= 0xbf58476d1ce4e5b9ull;
  x ^= x >> 27; x *= 0x94d049bb133111ebull;
  x ^= x >> 31; return x;
}

static __device__ __forceinline__ long long lookup_slot(const u64* __restrict__ tk, u32 cmask, u64 code){
  u32 h = (u32)mix64(code) & cmask;
#pragma unroll 1
  for(int p=0;p<PROBE_CAP;p++){
    u64 cur = tk[h];
    if(cur==code) return (long long)h;
    if(cur==KEMPTY) return -1;
    h=(h+1)&cmask;
  }
  return -1;
}

static __device__ __forceinline__ void atomAddF(float* p, float v){
#if defined(__gfx90a__) || defined(__gfx940__) || defined(__gfx941__) || defined(__gfx942__) || defined(__gfx950__)
  unsafeAtomicAdd(p, v);
#else
  atomicAdd(p, v);
#endif
}

static __device__ __forceinline__ void lds_add(float* p, float v){
  __hip_atomic_fetch_add(p, v, __ATOMIC_RELAXED, __HIP_MEMORY_SCOPE_WORKGROUP);
}
static __device__ __forceinline__ void lds_addu(u32* p, u32 v){
  __hip_atomic_fetch_add(p, v, __ATOMIC_RELAXED, __HIP_MEMORY_SCOPE_WORKGROUP);
}
static __device__ __forceinline__ u32 lds_addu_rtn(u32* p, u32 v){
  return __hip_atomic_fetch_add(p, v, __ATOMIC_RELAXED, __HIP_MEMORY_SCOPE_WORKGROUP);
}

static __device__ __forceinline__ void row_load(const float* __restrict__ p, float* o){
  const float4* q=(const float4*)p;
#pragma unroll
  for(int i=0;i<4;i++){ float4 v=q[i]; o[4*i]=v.x; o[4*i+1]=v.y; o[4*i+2]=v.z; o[4*i+3]=v.w; }
}
static __device__ __forceinline__ void row_store(float* __restrict__ p, const float* o){
  float4* q=(float4*)p;
#pragma unroll
  for(int i=0;i<4;i++) q[i]=make_float4(o[4*i],o[4*i+1],o[4*i+2],o[4*i+3]);
}

// ---------------- kernel 1: elevate/rank/bary + table insert; stores SLOT in inv ----------------
__global__ void __launch_bounds__(256)
k_setup(const float* __restrict__ feat, int N,
        u64* __restrict__ tabk, u32 cmask,
        u32* __restrict__ inv_slot, float* __restrict__ bary)
{
#pragma clang fp contract(off)
  int n = blockIdx.x*256 + threadIdx.x;
  if(n>=N) return;

  const float s0=3.4641016151377544f, s1=2.0f, s2=1.4142135623730951f,
              s3=1.0954451150103321f, s4=0.8944271909999159f;
  float c[5];
  c[0]=feat[n*5+0]*s0; c[1]=feat[n*5+1]*s1; c[2]=feat[n*5+2]*s2;
  c[3]=feat[n*5+3]*s3; c[4]=feat[n*5+4]*s4;

  float sfx[6]; sfx[5]=0.f;
#pragma unroll
  for(int i=4;i>=0;i--) sfx[i]=sfx[i+1]+c[i];
  float el[6];
  el[0]=sfx[0];
#pragma unroll
  for(int i=1;i<6;i++) el[i]=sfx[i]-(float)i*c[i-1];

  const float down=1.0f/6.0f;
  float rd[6], rem0[6], rdsum=0.f;
#pragma unroll
  for(int i=0;i<6;i++){ rd[i]=rintf(el[i]*down); rem0[i]=rd[i]*6.0f; rdsum+=rd[i]; }
  int sumi=(int)rdsum;

  float diff[6];
#pragma unroll
  for(int i=0;i<6;i++) diff[i]=(el[i]-rem0[i])*down;

  int rank[6];
#pragma unroll
  for(int i=0;i<6;i++){
    int r=0;
#pragma unroll
    for(int j=0;j<6;j++)
      r += (diff[j]>diff[i]) || (diff[j]==diff[i] && j<i);
    rank[i]=r+sumi;
  }
  int rem0i[6];
#pragma unroll
  for(int i=0;i<6;i++){
    rem0i[i]=(int)rem0[i];
    int sh=(rank[i]<0)-(rank[i]>5);
    rank[i]+=6*sh; rem0i[i]+=6*sh;
  }

  float b[7]={0.f,0.f,0.f,0.f,0.f,0.f,0.f};
#pragma unroll
  for(int i=0;i<6;i++){
    float t=(el[i]-(float)rem0i[i])*down;
    int k0=5-rank[i]; if(k0>=0&&k0<7) b[k0]+=t;
  }
#pragma unroll
  for(int i=0;i<6;i++){
    float t=(el[i]-(float)rem0i[i])*down;
    int k1=6-rank[i]; if(k1>=0&&k1<7) b[k1]-=t;
  }
  bary[(size_t)n*6+0]=(b[0]+1.0f)+b[6];
#pragma unroll
  for(int r=1;r<6;r++) bary[(size_t)n*6+r]=b[r];

#pragma unroll 1
  for(int r=0;r<6;r++){
    long long code=0;
#pragma unroll
    for(int i=0;i<5;i++){
      int key = rem0i[i] + ((rank[i] >= 6-r) ? (r-6) : r);
      code = code*2048 + (long long)(key+1024);
    }
    u32 h=(u32)mix64((u64)code)&cmask;
    u32 slot=0xFFFFFFFFu;
#pragma unroll 1
    for(int p=0;p<PROBE_CAP;p++){
      u64 cur=tabk[h];
      if(cur==(u64)code){ slot=h; break; }
      if(cur==KEMPTY){
        u64 old=atomicCAS((unsigned long long*)&tabk[h], KEMPTY, (u64)code);
        if(old==KEMPTY || old==(u64)code){ slot=h; break; }
      } else {
        h=(h+1)&cmask;
      }
    }
    inv_slot[(size_t)n*6+r]=slot;
  }
}

// ---------------- kernel 2: compact uids ----------------
__global__ void __launch_bounds__(256)
k_uid(const u64* __restrict__ tabk, u32 C, u32 Ucap, u32* __restrict__ tuid,
      u32* __restrict__ uidslot, u32* __restrict__ counter)
{
  u32 s=blockIdx.x*256+threadIdx.x;
  if(s>=C) return;
  if(tabk[s]==KEMPTY) return;
  u32 uid=atomicAdd(counter,1u);
  if(uid<Ucap) uidslot[uid]=s; else uid=0;
  tuid[s]=uid;
}

// ---------------- kernel 3: slot -> uid translation (always runs) ----------------
__global__ void __launch_bounds__(256)
k_translate(u32* __restrict__ inv, const u32* __restrict__ tuid, size_t M)
{
  size_t i=(size_t)blockIdx.x*256+threadIdx.x;
  if(i<M) inv[i]=tuid[inv[i]];
}

// ================= STREAM-SPLAT PATH (U <= THRESH) =================
// one block = (pass, sub): scans its point range coalescedly, accumulates the
// uid rows of its pass window in a 960-row LDS tile, flushes a partial tile.
// 1024 threads/block: same 64KB LDS per block -> still 2 blocks/CU, but
// 32 waves/CU instead of 8 (the round-10 latency-hiding fix).
__global__ void __launch_bounds__(1024, 8)
k_saccum(const u32* __restrict__ inv, const float* __restrict__ bary,
         const float* __restrict__ values, const u32* __restrict__ counter,
         u32 Ucap, int N, float* __restrict__ partial)
{
  __shared__ float acc[RPP*17];
  u32 U=*counter; if(U>Ucap) U=Ucap;
  if(U>THRESH) return;
  u32 P=(U+RPP-1)/RPP;
  u32 S=TOTAL_B/P;
  u32 j=blockIdx.x;
  if(j>=P*S) return;
  u32 pass=j/S, sub=j-pass*S;
  u32 lo=pass*RPP;
  u32 t=threadIdx.x;
  for(u32 x=t;x<RPP*17;x+=1024) acc[x]=0.f;
  __syncthreads();

  size_t p0=((size_t)sub*(size_t)N)/S;
  size_t p1=((size_t)(sub+1)*(size_t)N)/S;
  for(size_t i=p0+t;i<p1;i+=1024){
    const u32* ip=inv+i*6;
    const float* bp=bary+i*6;
    u32 u[6]; float w[6];
#pragma unroll
    for(int r=0;r<6;r++){ u[r]=ip[r]-lo; w[r]=bp[r]; }
    bool any=false;
#pragma unroll
    for(int r=0;r<6;r++) any = any | (u[r]<RPP);
    if(!any) continue;
    float v[16];
    row_load(values+(size_t)i*16, v);
#pragma unroll
    for(int r=0;r<6;r++){
      if(u[r]<RPP){
        u32 a=u[r]*17; float ww=w[r];
#pragma unroll
        for(int k=0;k<16;k++) lds_add(&acc[a+k], ww*v[k]);
      }
    }
  }
  __syncthreads();
  float* dst=partial+(size_t)j*(RPP*17);
  for(u32 x=t;x<RPP*17;x+=1024) dst[x]=acc[x];
}

// sum the S partial tiles of each pass into v0
__global__ void __launch_bounds__(256)
k_reduce(const float* __restrict__ partial, const u32* __restrict__ counter,
         u32 Ucap, float* __restrict__ v0)
{
  u32 U=*counter; if(U>Ucap) U=Ucap;
  if(U>THRESH) return;
  u32 P=(U+RPP-1)/RPP, S=TOTAL_B/P;
  const u32 RG=RPP/16;                    // 60 row-groups per pass
  u32 bid=blockIdx.x;
  u32 pass=bid/RG, rg=bid-pass*RG;
  if(pass>=P) return;
  u32 t=threadIdx.x;
  u32 r16=t>>4, k=t&15;
  u32 lrow=rg*16+r16;
  u32 gu=pass*RPP+lrow;
  const float* base=partial+((size_t)pass*S)*(RPP*17)+(size_t)lrow*17+k;
  float s=0.f;
  for(u32 ss=0;ss<S;ss++) s+=base[(size_t)ss*(RPP*17)];
  if(gu<U) v0[(size_t)gu*16+k]=s;
}

// ================= PARTITION PATH (U > THRESH) =================
__global__ void __launch_bounds__(256)
k_hist(const u32* __restrict__ inv, const u32* __restrict__ counter,
       u32* __restrict__ hist, size_t M)
{
  if(*counter<=THRESH) return;
  __shared__ u32 h[BINS];
  u32 t=threadIdx.x, b=blockIdx.x;
#pragma unroll
  for(int j=0;j<(int)(BINS/256);j++) h[t+j*256]=0;
  __syncthreads();
  size_t base=(size_t)b*CHUNK;
#pragma unroll
  for(int j=0;j<(int)(CHUNK/256);j++){
    size_t i=base + (size_t)j*256 + t;
    if(i<M){
      u32 u=inv[i];
      lds_addu(&h[u&(BINS-1)],1u);
    }
  }
  __syncthreads();
#pragma unroll
  for(int j=0;j<(int)(BINS/256);j++){
    u32 bin=t+j*256;
    hist[(size_t)b*BINS+bin]=h[bin];
  }
}

__global__ void __launch_bounds__(256)
k_transpose(const u32* __restrict__ in, u32* __restrict__ out, u32 R, u32 C,
            const u32* __restrict__ counter)
{
  if(*counter<=THRESH) return;
  __shared__ u32 tile[32][33];
  u32 bx=blockIdx.x, by=blockIdx.y;
  u32 tx=threadIdx.x&31, ty=threadIdx.x>>5;
  u32 c0=bx*32, r0=by*32;
#pragma unroll
  for(u32 j=0;j<32;j+=8){
    u32 r=r0+ty+j, c=c0+tx;
    if(r<R && c<C) tile[ty+j][tx]=in[(size_t)r*C+c];
  }
  __syncthreads();
#pragma unroll
  for(u32 j=0;j<32;j+=8){
    u32 c=c0+ty+j, r=r0+tx;
    if(c<C && r<R) out[(size_t)c*R+r]=tile[tx][ty+j];
  }
}

__global__ void __launch_bounds__(256)
k_scan1(const u32* __restrict__ v, u32* __restrict__ bsum, const u32* __restrict__ counter)
{
  if(*counter<=THRESH) return;
  __shared__ u32 sm[256];
  u32 t=threadIdx.x, b=blockIdx.x;
  size_t base=((size_t)b*256+t)*4;
  u32 s=v[base]+v[base+1]+v[base+2]+v[base+3];
  sm[t]=s; __syncthreads();
  for(int o=128;o>0;o>>=1){ if(t<(u32)o) sm[t]+=sm[t+o]; __syncthreads(); }
  if(t==0) bsum[b]=sm[0];
}

__global__ void __launch_bounds__(256)
k_scan2(u32* __restrict__ bsum, u32 nb, const u32* __restrict__ counter)
{
  if(*counter<=THRESH) return;
  __shared__ u32 sm[256];
  u32 t=threadIdx.x;
  u32 per=(nb+255)/256;
  u32 lo=t*per, hi=lo+per; if(hi>nb) hi=nb; if(lo>nb) lo=nb;
  u32 tot=0;
  for(u32 i=lo;i<hi;i++) tot+=bsum[i];
  sm[t]=tot; __syncthreads();
  for(int o=1;o<256;o<<=1){
    u32 v=sm[t]; u32 a=(t>=(u32)o)?sm[t-o]:0u; __syncthreads();
    sm[t]=v+a; __syncthreads();
  }
  u32 run=sm[t]-tot;
  for(u32 i=lo;i<hi;i++){ u32 c=bsum[i]; bsum[i]=run; run+=c; }
}

__global__ void __launch_bounds__(256)
k_scan3(u32* __restrict__ v, const u32* __restrict__ bsum, const u32* __restrict__ counter)
{
  if(*counter<=THRESH) return;
  __shared__ u32 sm[256];
  u32 t=threadIdx.x, b=blockIdx.x;
  size_t base=((size_t)b*256+t)*4;
  u32 c[4]; u32 tot=0;
#pragma unroll
  for(int j=0;j<4;j++){ c[j]=v[base+j]; tot+=c[j]; }
  sm[t]=tot; __syncthreads();
  for(int o=1;o<256;o<<=1){
    u32 x=sm[t]; u32 a=(t>=(u32)o)?sm[t-o]:0u; __syncthreads();
    sm[t]=x+a; __syncthreads();
  }
  u32 run=bsum[b]+sm[t]-tot;
#pragma unroll
  for(int j=0;j<4;j++){ v[base+j]=run; run+=c[j]; }
}

__global__ void __launch_bounds__(256)
k_part(const u32* __restrict__ inv, const float* __restrict__ bary,
       const u32* __restrict__ histT, u32 nb,
       u32* __restrict__ skey, float* __restrict__ sw, size_t M,
       const u32* __restrict__ counter)
{
  if(*counter<=THRESH) return;
  __shared__ u32 cur[BINS];
  u32 t=threadIdx.x, b=blockIdx.x;
#pragma unroll
  for(int j=0;j<(int)(BINS/256);j++){
    u32 bin=t+j*256;
    cur[bin]=histT[(size_t)bin*nb+b];
  }
  __syncthreads();
  size_t base=(size_t)b*CHUNK;
#pragma unroll
  for(int j=0;j<(int)(CHUNK/256);j++){
    size_t i=base+(size_t)j*256+t;
    if(i<M){
      u32 u=inv[i];
      u32 pos=lds_addu_rtn(&cur[u&(BINS-1)],1u);
      skey[pos]=((u>>12)<<20)|((u32)(i/6u));
      sw[pos]=bary[i];
    }
  }
}

__global__ void __launch_bounds__(256)
k_queue(const u32* __restrict__ histT, u32 nb, size_t M,
        u32* __restrict__ q, u32* __restrict__ qn, const u32* __restrict__ counter)
{
  if(*counter<=THRESH) return;
  u32 b=blockIdx.x*256+threadIdx.x;
  if(b>=BINS) return;
  size_t s=histT[(size_t)b*nb];
  size_t e=(b+1<BINS)? (size_t)histT[(size_t)(b+1)*nb] : M;
  u32 sz=(u32)(e-s);
  if(sz==0) return;
  u32 G=(sz+SPLIT-1)/SPLIT; if(G>1023u) G=1023u;
  u32 base=atomicAdd(qn,G);
  for(u32 g=0; g<G; g++) q[base+g] = b | (g<<12) | (G<<22);
}

__global__ void __launch_bounds__(256)
k_accum(const u32* __restrict__ q, const u32* __restrict__ qn,
        const u32* __restrict__ skey, const float* __restrict__ sw,
        const float* __restrict__ values, const u32* __restrict__ histT,
        u32 nb, u32 rows, size_t M, float* __restrict__ v0)
{
  __shared__ float acc[4352];
  u32 j=blockIdx.x;
  if(j>=*qn) return;
  u32 ent=q[j];
  u32 b=ent&4095u, g=(ent>>12)&1023u, G=ent>>22;
  size_t s0=histT[(size_t)b*nb];
  size_t e0=(b+1<BINS)? (size_t)histT[(size_t)(b+1)*nb] : M;
  u32 sz=(u32)(e0-s0);
  u32 chunk=(sz+G-1)/G;
  size_t s=s0+(size_t)g*chunk;
  size_t e=s+chunk; if(e>e0) e=e0;

  u32 t=threadIdx.x;
  for(u32 x=t;x<rows*17;x+=256) acc[x]=0.f;
  __syncthreads();

  if(G==1){
    size_t base=s;
    for(; base+512<=e; base+=512){
      size_t i0=base+t, i1=base+256+t;
      u32 key0=skey[i0], key1=skey[i1];
      float w0=sw[i0], w1=sw[i1];
      float r0[16], r1[16];
      row_load(values+(size_t)(key0&0xFFFFFu)*16, r0);
      row_load(values+(size_t)(key1&0xFFFFFu)*16, r1);
      u32 a0=(key0>>20)*17, a1=(key1>>20)*17;
#pragma unroll
      for(int k=0;k<16;k++) lds_add(&acc[a0+k], w0*r0[k]);
#pragma unroll
      for(int k=0;k<16;k++) lds_add(&acc[a1+k], w1*r1[k]);
    }
    for(; base<e; base+=256){
      size_t ei=base+t;
      if(ei<e){
        u32 key=skey[ei]; float w=sw[ei];
        float r[16];
        row_load(values+(size_t)(key&0xFFFFFu)*16, r);
        u32 a=(key>>20)*17;
#pragma unroll
        for(int k=0;k<16;k++) lds_add(&acc[a+k], w*r[k]);
      }
    }
  } else {
    u32 gr=t>>4, k=t&15;
    size_t base=s;
    for(; base+128<=e; base+=128){
      u32 key[8]; float w[8]; float x[8];
#pragma unroll
      for(int u8=0;u8<8;u8++){ size_t ei=base+(size_t)u8*16+gr; key[u8]=skey[ei]; w[u8]=sw[ei]; }
#pragma unroll
      for(int u8=0;u8<8;u8++){ x[u8]=values[(size_t)(key[u8]&0xFFFFFu)*16+k]; }
#pragma unroll
      for(int u8=0;u8<8;u8++) lds_add(&acc[(key[u8]>>20)*17+k], w[u8]*x[u8]);
    }
    for(; base<e; base+=16){
      size_t ei=base+gr;
      if(ei<e){
        u32 key=skey[ei]; float w=sw[ei];
        float x=values[(size_t)(key&0xFFFFFu)*16+k];
        lds_add(&acc[(key>>20)*17+k], w*x);
      }
    }
  }
  __syncthreads();

  if(G==1){
    for(u32 x=t;x<rows*16;x+=256){
      u32 row=x>>4, kk=x&15;
      v0[(size_t)((row<<12)|b)*16+kk]=acc[row*17+kk];
    }
  } else {
    for(u32 x=t;x<rows*16;x+=256){
      u32 row=x>>4, kk=x&15;
      float a=acc[row*17+kk];
      if(a!=0.f) atomAddF(&v0[(size_t)((row<<12)|b)*16+kk], a);
    }
  }
}

// ---------------- blur ----------------
__global__ void __launch_bounds__(256)
k_blur(const u64* __restrict__ tabk, const u32* __restrict__ tuid, u32 cmask,
       const u32* __restrict__ uidslot, const u32* __restrict__ counter, u32 Ucap,
       long long delta, const float* __restrict__ vin, float* __restrict__ vout)
{
  u32 m=blockIdx.x*256+threadIdx.x;
  u32 U=*counter; if(U>Ucap) U=Ucap;
  if(m>=U) return;
  long long code=(long long)tabk[uidslot[m]];
  long long sp=lookup_slot(tabk,cmask,(u64)(code+delta));
  long long sm=lookup_slot(tabk,cmask,(u64)(code-delta));
  float acc[16];
  row_load(vin+(size_t)m*16, acc);
#pragma unroll
  for(int k=0;k<16;k++) acc[k]*=0.5f;
  if(sp>=0){
    u32 u=tuid[sp]; float t[16]; row_load(vin+(size_t)u*16,t);
#pragma unroll
    for(int k=0;k<16;k++) acc[k]+=0.25f*t[k];
  }
  if(sm>=0){
    u32 u=tuid[sm]; float t[16]; row_load(vin+(size_t)u*16,t);
#pragma unroll
    for(int k=0;k<16;k++) acc[k]+=0.25f*t[k];
  }
  row_store(vout+(size_t)m*16, acc);
}

// ---------------- slice ----------------
__global__ void __launch_bounds__(256)
k_slice(const u32* __restrict__ inv, const float* __restrict__ bary,
        const float* __restrict__ val, int N, float* __restrict__ out)
{
  int n=blockIdx.x*256+threadIdx.x;
  if(n>=N) return;
  u32 u[6]; float w[6];
#pragma unroll
  for(int r=0;r<6;r++){ u[r]=inv[(size_t)n*6+r]; w[r]=bary[(size_t)n*6+r]; }
  float t6[6][16];
#pragma unroll
  for(int r=0;r<6;r++) row_load(val+(size_t)u[r]*16, t6[r]);
  float acc[16];
#pragma unroll
  for(int k=0;k<16;k++){
    float a=w[0]*t6[0][k];
#pragma unroll
    for(int r=1;r<6;r++) a+=w[r]*t6[r][k];
    acc[k]=a;
  }
  const float alpha=0.9696969696969697f;
  float4* q=(float4*)(out+(size_t)n*16);
#pragma unroll
  for(int i=0;i<4;i++) q[i]=make_float4(alpha*acc[4*i],alpha*acc[4*i+1],alpha*acc[4*i+2],alpha*acc[4*i+3]);
}

__global__ void k_diag(float* out, float v){ out[0]=v; }

// ---------------- host ----------------
extern "C" void kernel_launch(void* const* d_in, const int* in_sizes, int n_in,
                              void* d_out, int out_size, void* d_ws, size_t ws_size,
                              hipStream_t stream)
{
  const float* feat   =(const float*)d_in[0];
  const float* values =(const float*)d_in[1];
  float* out=(float*)d_out;
  int N=in_sizes[0]/5;
  size_t M=(size_t)N*6;

  u32 nb=(u32)((M+CHUNK-1)/CHUNK);
  size_t K=(size_t)nb*BINS;
  const u32 QCAP=16384;

  // v1 union: partition scratch {hist,histT,skey,sw,bsum,q,qn}  OR  stream partial tiles
  size_t partial_bytes=(size_t)TOTAL_B*(RPP*17)*4;   // 33.4 MB
  auto v1bytes=[&](size_t U)->size_t{
    size_t a=U*64;
    size_t b=K*4+K*4+M*4+M*4+(K/1024)*4+QCAP*4+1024;
    size_t c=partial_bytes;
    size_t m1=a>b?a:b;
    return m1>c?m1:c;
  };
  auto need=[&](int lC,int lU)->size_t{
    size_t C=1ull<<lC, U=1ull<<lU, s=0;
    auto al=[&](size_t b){ s=(s+255)&~(size_t)255; s+=b; };
    al(4); al(M*4); al(M*4); al(C*8); al(C*4); al(U*4); al(U*64); al(v1bytes(U));
    return s+256;
  };
  const int prefs[4][2]={{22,20},{21,20},{21,19},{20,18}};
  int lC=0,lU=0;
  for(int i=0;i<4;i++){ if(need(prefs[i][0],prefs[i][1])<=ws_size){ lC=prefs[i][0]; lU=prefs[i][1]; break; } }
  if(!lC){
    hipMemsetAsync(d_out,0,(size_t)out_size*sizeof(float),stream);
    k_diag<<<1,1,0,stream>>>(out,(float)(ws_size>>20));
    return;
  }

  size_t C=1ull<<lC, Ucap=1ull<<lU; u32 cmask=(u32)(C-1);
  char* base=(char*)d_ws; size_t offb=0;
  auto carve=[&](size_t b)->char*{ offb=(offb+255)&~(size_t)255; char* p=base+offb; offb+=b; return p; };
  u32*   counter=(u32*)carve(4);
  u32*   inv    =(u32*)carve(M*4);
  float* bary   =(float*)carve(M*4);
  u64*   tabk   =(u64*)carve(C*8);
  u32*   tuid   =(u32*)carve(C*4);
  u32*   uidslot=(u32*)carve(Ucap*4);
  float* v0     =(float*)carve(Ucap*64);
  float* v1     =(float*)carve(v1bytes(Ucap));

  // partition scratch aliases
  u32*   hist =(u32*)v1;
  u32*   histT=hist+K;
  u32*   skey =histT+K;
  float* sw   =(float*)(skey+M);
  u32*   bsum =(u32*)(sw+M);
  u32*   q    =bsum+(K/1024);
  u32*   qn   =q+QCAP;
  // stream scratch alias
  float* partial=(float*)v1;

  hipMemsetAsync(counter,0,4,stream);
  hipMemsetAsync(tabk,0xFF,C*8,stream);
  hipMemsetAsync(v0,0,Ucap*64,stream);

  const int B=256;
  k_setup    <<<(N+B-1)/B,B,0,stream>>>(feat,N,tabk,cmask,inv,bary);
  k_uid      <<<(u32)((C+B-1)/B),B,0,stream>>>(tabk,(u32)C,(u32)Ucap,tuid,uidslot,counter);
  k_translate<<<(u32)((M+B-1)/B),B,0,stream>>>(inv,tuid,M);

  // ---- stream path (dead if U>THRESH) ----
  k_saccum<<<TOTAL_B,1024,0,stream>>>(inv,bary,values,counter,(u32)Ucap,N,partial);
  k_reduce<<<PMAX*(RPP/16),B,0,stream>>>(partial,counter,(u32)Ucap,v0);

  // ---- partition path (dead if U<=THRESH) ----
  hipMemsetAsync(qn,0,4,stream);   // after stream path (qn aliases partial region)
  k_hist <<<nb,B,0,stream>>>(inv,counter,hist,M);
  {
    dim3 g((BINS+31)/32,(nb+31)/32);
    k_transpose<<<g,B,0,stream>>>(hist,histT,nb,BINS,counter);
  }
  u32 sb=(u32)(K/1024);
  k_scan1<<<sb,B,0,stream>>>(histT,bsum,counter);
  k_scan2<<<1 ,B,0,stream>>>(bsum,sb,counter);
  k_scan3<<<sb,B,0,stream>>>(histT,bsum,counter);
  k_part <<<nb,B,0,stream>>>(inv,bary,histT,nb,skey,sw,M,counter);
  k_queue<<<(BINS+B-1)/B,B,0,stream>>>(histT,nb,M,q,qn,counter);

  u32 rows=(u32)(Ucap>>12);
  k_accum<<<QCAP,B,0,stream>>>(q,qn,skey,sw,values,histT,nb,rows,M,v0);

  const long long P[5]={1ll,2048ll,1ll<<22,1ll<<33,1ll<<44};
  const long long SUM=P[0]+P[1]+P[2]+P[3]+P[4];
  u32 gb=(u32)((Ucap+B-1)/B);
  float* a=v0; float* bb=v1;
  for(int j=0;j<6;j++){
    long long delta=(j<5)? (SUM-6*P[4-j]) : SUM;
    k_blur<<<gb,B,0,stream>>>(tabk,tuid,cmask,uidslot,counter,(u32)Ucap,delta,a,bb);
    float* t=a; a=bb; bb=t;
  }
  k_slice<<<(N+B-1)/B,B,0,stream>>>(inv,bary,a,N,out);
}